// Round 1
// 508.458 us; speedup vs baseline: 1.0125x; 1.0125x over previous
//
#include <hip/hip_runtime.h>
#include <math.h>

typedef unsigned short u16;
typedef unsigned int u32;

// ---- problem constants ----
constexpr int Bb = 4, Ll = 2048, DM = 1024, DI = 2048, DS = 16, DTR = 64, KC = 4;
constexpr int M = Bb * Ll;            // 8192 rows
constexpr int NPAD = 128;             // padded x_dbl width (64 + 2*16 = 96 -> 128)
constexpr int NCHUNK = 16;            // scan chunks
constexpr int LC = Ll / NCHUNK;       // 128 steps per chunk
constexpr int LDXZ = 4096;            // xz row stride (xr|z interleaved)

// ---- bf16 helpers on raw u16 ----
__device__ __forceinline__ float b2f(u16 u) {
    return __uint_as_float(((u32)u) << 16);
}
__device__ __forceinline__ u16 f2b(float f) {
    u32 x = __float_as_uint(f);
    u32 r = (x + 0x7fffu + ((x >> 16) & 1u)) >> 16;   // round-to-nearest-even
    return (u16)r;
}

typedef __attribute__((ext_vector_type(8))) short short8;
typedef __attribute__((ext_vector_type(4))) short short4v;
typedef __attribute__((ext_vector_type(4))) float floatx4;

// async global->LDS, 16B per lane; LDS dest = wave-uniform base + lane*16
__device__ __forceinline__ void gload16(const u16* g, u16* l) {
    __builtin_amdgcn_global_load_lds(
        (const __attribute__((address_space(1))) void*)g,
        (__attribute__((address_space(3))) void*)l,
        16, 0, 0);
}

// a^(s+1) for s=0..15 from base a, tree form (15 muls, depth 4)
__device__ __forceinline__ void pow_tree(float a, float* aa) {
    float a2 = a * a, a4 = a2 * a2, a8 = a4 * a4;
    aa[0] = a;        aa[1] = a2;       aa[2] = a * a2;   aa[3] = a4;
    aa[4] = a * a4;   aa[5] = a2 * a4;  aa[6] = aa[2] * a4; aa[7] = a8;
    aa[8] = a * a8;   aa[9] = a2 * a8;  aa[10] = aa[2] * a8; aa[11] = a4 * a8;
    aa[12] = aa[4] * a8; aa[13] = aa[5] * a8; aa[14] = aa[6] * a8; aa[15] = a8 * a8;
}

// =====================================================================
// Big-tile GEMM: C(MxN) = A(MxK) * B(NxK)^T, bf16 in, fp32 MFMA acc.
// 256x256 tile, 8 waves (2M x 4N), BK=32, 4-deep circular LDS buffer
// (128 KiB total), 2 phases per K-tile with counted vmcnt (T3+T4) and
// setprio around the MFMA cluster (T5).  K-chunk rotation swizzle
// (conflict-free, same scheme as the verified 128^2 kernel).
// Requires K % 32 == 0 and K >= 96.
// OUTM: 0 = bf16 store, 1 = fp32 store.
// =====================================================================
template<int OUTM>
__global__ __launch_bounds__(512, 2) void gemm256(
    const u16* __restrict__ A, const u16* __restrict__ Bm,
    void* __restrict__ Cv,
    int K, int lda, int ldb, int ldc)
{
    __shared__ alignas(16) u16 ldsA[4][256 * 32];   // 64 KiB
    __shared__ alignas(16) u16 ldsB[4][256 * 32];   // 64 KiB

    const int lane = threadIdx.x & 63;
    const int wave = threadIdx.x >> 6;     // 0..7
    const int wr = wave >> 2;              // 0..1  (M half of the tile)
    const int wc = wave & 3;               // 0..3  (N quarter)
    const int m0 = blockIdx.y * 256;
    const int n0 = blockIdx.x * 256;

    // ---- staging addresses: wave stages rows [wave*32, wave*32+32) ----
    const int lrow = lane >> 2;                               // 0..15
    const int skc  = (((lane & 3) + (lane >> 3)) & 3) * 8;    // k-chunk rotation
    const u16* pA = A  + (size_t)(m0 + wave * 32 + lrow) * lda + skc;
    const u16* pB = Bm + (size_t)(n0 + wave * 32 + lrow) * ldb + skc;
    const int ldst = wave * 1024;          // LDS element offset of this wave's 32 rows

    // ---- fragment read addresses (rotation-inverse slot) ----
    const int r16 = lane & 15;
    const int quad = lane >> 4;
    const int slot = (quad + 4 - ((r16 >> 1) & 3)) & 3;
    const int aoff = (wr * 128 + r16) * 32 + slot * 8;
    const int boff = (wc * 64  + r16) * 32 + slot * 8;

    const int NT = K >> 5;                 // K-tiles of 32

    floatx4 acc[8][4] = {};

    // ---- prologue: stage tiles 0,1,2 (12 loads/thread) ----
#pragma unroll
    for (int t = 0; t < 3; ++t) {
        gload16(pA + t * 32,            &ldsA[t][ldst]);
        gload16(pA + t * 32 + 16 * lda, &ldsA[t][ldst + 512]);
        gload16(pB + t * 32,            &ldsB[t][ldst]);
        gload16(pB + t * 32 + 16 * ldb, &ldsB[t][ldst + 512]);
    }
    asm volatile("s_waitcnt vmcnt(8)" ::: "memory");   // tile 0 landed
    __builtin_amdgcn_sched_barrier(0);
    __builtin_amdgcn_s_barrier();

    for (int t = 0; t < NT; ++t) {
        const u16* la = &ldsA[t & 3][aoff];
        const u16* lb = &ldsB[t & 3][boff];
        short8 af[8], bf[4];

        // ================= phase A: M-frags 0-3 x all N =================
#pragma unroll
        for (int i = 0; i < 4; ++i) af[i] = *(const short8*)(la + i * 512);
#pragma unroll
        for (int j = 0; j < 4; ++j) bf[j] = *(const short8*)(lb + j * 512);
        if (t + 3 < NT) {                  // stage A-tile of t+3 (buf freed at t-1)
            const u16* s = pA + (t + 3) * 32;
            u16* d = &ldsA[(t + 3) & 3][ldst];
            gload16(s, d);
            gload16(s + 16 * lda, d + 512);
        }
        __builtin_amdgcn_sched_barrier(0);
        __builtin_amdgcn_s_barrier();
        asm volatile("s_waitcnt lgkmcnt(0)" ::: "memory");
        __builtin_amdgcn_sched_barrier(0);
        __builtin_amdgcn_s_setprio(1);
#pragma unroll
        for (int i = 0; i < 4; ++i)
#pragma unroll
            for (int j = 0; j < 4; ++j)
                acc[i][j] = __builtin_amdgcn_mfma_f32_16x16x32_bf16(
                    af[i], bf[j], acc[i][j], 0, 0, 0);
        __builtin_amdgcn_s_setprio(0);
        __builtin_amdgcn_sched_barrier(0);
        __builtin_amdgcn_s_barrier();

        // ================= phase B: M-frags 4-7 x all N =================
#pragma unroll
        for (int i = 4; i < 8; ++i) af[i] = *(const short8*)(la + i * 512);
        if (t + 3 < NT) {                  // stage B-tile of t+3
            const u16* s = pB + (t + 3) * 32;
            u16* d = &ldsB[(t + 3) & 3][ldst];
            gload16(s, d);
            gload16(s + 16 * ldb, d + 512);
        }
        __builtin_amdgcn_sched_barrier(0);
        __builtin_amdgcn_s_barrier();
        asm volatile("s_waitcnt lgkmcnt(0)" ::: "memory");
        __builtin_amdgcn_sched_barrier(0);
        __builtin_amdgcn_s_setprio(1);
#pragma unroll
        for (int i = 4; i < 8; ++i)
#pragma unroll
            for (int j = 0; j < 4; ++j)
                acc[i][j] = __builtin_amdgcn_mfma_f32_16x16x32_bf16(
                    af[i], bf[j], acc[i][j], 0, 0, 0);
        __builtin_amdgcn_s_setprio(0);
        // counted vmcnt, once per K-tile; never 0 in steady state
        if (t + 3 < NT)      asm volatile("s_waitcnt vmcnt(8)" ::: "memory");
        else if (t + 2 < NT) asm volatile("s_waitcnt vmcnt(4)" ::: "memory");
        else if (t + 1 < NT) asm volatile("s_waitcnt vmcnt(0)" ::: "memory");
        __builtin_amdgcn_sched_barrier(0);
        __builtin_amdgcn_s_barrier();
    }

    // D layout: col = lane&15, row = quad*4 + r   [verified m89/m91]
    const int mw = m0 + wr * 128;
    const int nw = n0 + wc * 64;
    const int rb = quad * 4;
#pragma unroll
    for (int i = 0; i < 8; ++i) {
#pragma unroll
        for (int j = 0; j < 4; ++j) {
            const int n = nw + j * 16 + r16;
#pragma unroll
            for (int r = 0; r < 4; ++r) {
                const int m = mw + i * 16 + rb + r;
                float v = acc[i][j][r];
                if (OUTM == 1)
                    ((float*)Cv)[(size_t)m * ldc + n] = v;
                else
                    ((u16*)Cv)[(size_t)m * ldc + n] = f2b(v);
            }
        }
    }
}

// =====================================================================
// C(MxN) = A(MxK) * B(NxK)^T, bf16 in, fp32 MFMA acc.  m97 structure
// + k-chunk rotation swizzle (conflict-free ds_read_b128).
// OUTM: 2 = softplus(acc + bias[n]) bf16,
//       4 = split-K partial: fp32 store, k-slice = blockIdx.z
// (kept for the small-K / small-N GEMMs)
// =====================================================================
template<int OUTM>
__global__ __launch_bounds__(256) void gemm_bt(
    const u16* __restrict__ A, const u16* __restrict__ Bm,
    void* __restrict__ Cv, const float* __restrict__ bias,
    int K, int lda, int ldb, int ldc)
{
    __shared__ alignas(16) u16 ldsA[128 * 32];
    __shared__ alignas(16) u16 ldsB[128 * 32];

    const int lane = threadIdx.x & 63;
    const int wave = threadIdx.x >> 6;
    const int wr = wave >> 1, wc = wave & 1;
    const int m0 = blockIdx.y * 128;
    const int n0 = blockIdx.x * 128;
    const int koff = (OUTM == 4) ? blockIdx.z * K : 0;

    const int srow = wave * 32 + (lane >> 2);
    const int skc  = (((lane & 3) + (lane >> 3)) & 3) * 8;
    const u16* Ag = A + (size_t)(m0 + srow) * lda + skc + koff;
    const u16* Bg = Bm + (size_t)(n0 + srow) * ldb + skc + koff;
    u16* lA = &ldsA[wave * 1024];
    u16* lB = &ldsB[wave * 1024];

    const int r16 = lane & 15;
    const int quad = lane >> 4;
    const int slot = (quad + 4 - ((r16 >> 1) & 3)) & 3;
    const u16* arow = &ldsA[(wr * 64 + r16) * 32 + slot * 8];
    const u16* brow = &ldsB[(wc * 64 + r16) * 32 + slot * 8];

    floatx4 acc[4][4] = {};

    for (int k0 = 0; k0 < K; k0 += 32) {
        gload16(Ag + k0,                    lA);
        gload16(Ag + k0 + (size_t)16 * lda, lA + 512);
        gload16(Bg + k0,                    lB);
        gload16(Bg + k0 + (size_t)16 * ldb, lB + 512);
        __syncthreads();

        short8 af[4], bf[4];
#pragma unroll
        for (int i = 0; i < 4; i++) af[i] = *(const short8*)(arow + i * 16 * 32);
#pragma unroll
        for (int j = 0; j < 4; j++) bf[j] = *(const short8*)(brow + j * 16 * 32);
#pragma unroll
        for (int i = 0; i < 4; i++)
#pragma unroll
            for (int j = 0; j < 4; j++)
                acc[i][j] = __builtin_amdgcn_mfma_f32_16x16x32_bf16(
                    af[i], bf[j], acc[i][j], 0, 0, 0);
        __syncthreads();
    }

    // D layout: col = lane&15, row = quad*4 + r   [verified m89/m91]
    const int mw = m0 + wr * 64;
    const int nw = n0 + wc * 64;
    const int rb = quad * 4;
#pragma unroll
    for (int i = 0; i < 4; i++) {
#pragma unroll
        for (int j = 0; j < 4; j++) {
            const int n = nw + j * 16 + r16;
#pragma unroll
            for (int r = 0; r < 4; r++) {
                const int m = mw + i * 16 + rb + r;
                float v = acc[i][j][r];
                if (OUTM == 2) {
                    v += bias[n];
                    v = (v > 20.f) ? v : log1pf(__expf(v));
                }
                if (OUTM == 4)
                    ((float*)Cv)[((size_t)blockIdx.z * M + m) * ldc + n] = v;
                else if (OUTM == 1)
                    ((float*)Cv)[(size_t)m * ldc + n] = v;
                else
                    ((u16*)Cv)[(size_t)m * ldc + n] = f2b(v);
            }
        }
    }
}

// =====================================================================
// reduce 4 split-K fp32 partials -> bf16 xdbl + fp32 bcf sideband
// =====================================================================
__global__ __launch_bounds__(256) void redk_gemm3(
    const float* __restrict__ part, u16* __restrict__ xdbl,
    float* __restrict__ bcf)
{
    const int t = blockIdx.x * 256 + threadIdx.x;   // over M*32
    const int n4 = (t & 31) * 4;
    const int m = t >> 5;
    const size_t stride = (size_t)M * NPAD;
    const float* p = part + (size_t)m * NPAD + n4;
    floatx4 acc = *(const floatx4*)(p)
                + *(const floatx4*)(p + stride)
                + *(const floatx4*)(p + 2 * stride)
                + *(const floatx4*)(p + 3 * stride);
    short4v ob;
#pragma unroll
    for (int j = 0; j < 4; j++) ob[j] = (short)f2b(acc[j]);
    *(short4v*)(xdbl + (size_t)m * NPAD + n4) = ob;
    if (n4 >= 64 && n4 < 96)
        *(floatx4*)(bcf + (size_t)m * 32 + (n4 - 64)) = acc;
}

// =====================================================================
__global__ __launch_bounds__(256) void cvt_f2b(
    const float* __restrict__ in, u16* __restrict__ out, int n)
{
    int i = blockIdx.x * blockDim.x + threadIdx.x;
    if (i < n) out[i] = f2b(in[i]);
}

// merged weight prep: W_in cvt | W_x pad | W_dt cvt | W_out cvt
__global__ __launch_bounds__(256) void prep_weights(
    const float* __restrict__ W_in, const float* __restrict__ W_x,
    const float* __restrict__ W_dt, const float* __restrict__ W_out,
    u16* __restrict__ wibf, u16* __restrict__ wxp,
    u16* __restrict__ wdtb, u16* __restrict__ woutb)
{
    constexpr int N1 = 2 * DI * DM;          // 4194304
    constexpr int N2 = NPAD * DI;            // 262144
    constexpr int N3 = DI * DTR;             // 131072
    int idx = blockIdx.x * blockDim.x + threadIdx.x;
    if (idx < N1) {
        wibf[idx] = f2b(W_in[idx]);
    } else if (idx < N1 + N2) {
        int i = idx - N1;
        int r = i >> 11, c = i & 2047;
        wxp[i] = (r < 96) ? f2b(W_x[r * 2048 + c]) : (u16)0;
    } else if (idx < N1 + N2 + N3) {
        int i = idx - N1 - N2;
        wdtb[i] = f2b(W_dt[i]);
    } else {
        int i = idx - N1 - N2 - N3;
        woutb[i] = f2b(W_out[i]);
    }
}

// =====================================================================
// Depthwise causal conv (K=4) + SiLU, vectorized.
// =====================================================================
__global__ __launch_bounds__(256) void conv_silu(
    const u16* __restrict__ xz, const float* __restrict__ conv_w,
    const float* __restrict__ conv_b, u16* __restrict__ xs)
{
    const int m = blockIdx.x;
    const int d0 = threadIdx.x * 8;
    const int l = m & (Ll - 1);

    float acc[8];
    {
        floatx4 cb0 = *(const floatx4*)(conv_b + d0);
        floatx4 cb1 = *(const floatx4*)(conv_b + d0 + 4);
#pragma unroll
        for (int j = 0; j < 4; j++) { acc[j] = cb0[j]; acc[4 + j] = cb1[j]; }
    }
    float w[8][KC];
#pragma unroll
    for (int jd = 0; jd < 8; jd++) {
        floatx4 wv = *(const floatx4*)(conv_w + (d0 + jd) * KC);
#pragma unroll
        for (int k = 0; k < KC; k++) w[jd][k] = wv[k];
    }
#pragma unroll
    for (int k = 0; k < KC; k++) {
        int li = l - (KC - 1) + k;
        if (li >= 0) {
            short8 xv = *(const short8*)(xz + (size_t)(m - (KC - 1) + k) * LDXZ + d0);
#pragma unroll
            for (int jd = 0; jd < 8; jd++)
                acc[jd] += b2f((u16)xv[jd]) * w[jd][k];
        }
    }
    short8 o;
#pragma unroll
    for (int jd = 0; jd < 8; jd++) {
        float s = acc[jd] / (1.f + __expf(-acc[jd]));
        o[jd] = (short)f2b(s);
    }
    *(short8*)(xs + (size_t)m * DI + d0) = o;
}

// =====================================================================
// Chunked selective scan.  One THREAD per (channel, chunk); 16 states in
// registers; coalesced dt/xs/z.  B/C panel (shared by the whole block:
// same (b, chunk)) staged into 16 KB LDS once, then broadcast ds_reads.
// Fast path (A_log = log(1..16), wave-uniform check): 1 exp + pow tree.
// =====================================================================
__global__ __launch_bounds__(256) void scan_p1(
    const u16* __restrict__ xzdt, const u16* __restrict__ xs,
    const float* __restrict__ bcf, const float* __restrict__ A_log,
    float* __restrict__ scr_P, float* __restrict__ scr_hend)
{
    __shared__ alignas(16) float bcs[LC * 32];   // 16 KB

    const int d = blockIdx.x * 256 + threadIdx.x;
    const int b = blockIdx.y;
    const int c = blockIdx.z;
    const int m0 = b * Ll + c * LC;

    // cooperative stage of the B/C panel (coalesced float4)
    {
        const float* bc_g = bcf + (size_t)m0 * 32;
#pragma unroll
        for (int j = 0; j < 4; j++) {
            int idx = j * 1024 + threadIdx.x * 4;
            *(floatx4*)(bcs + idx) = *(const floatx4*)(bc_g + idx);
        }
    }

    const float ad0 = -__expf(A_log[0]);
    float adl[DS];
    bool fast = true;
#pragma unroll
    for (int s = 0; s < DS; s++) {
        float av = -__expf(A_log[s]);
        adl[s] = av;
        float kr = (float)(s + 1);
        if (fabsf(av / ad0 - kr) > 1e-4f * kr) fast = false;
    }

    const u16* dt_p = xzdt + (size_t)m0 * LDXZ + d;
    const u16* xs_p = xs + (size_t)m0 * DI + d;

    float h[DS] = {};
    float P[DS];
#pragma unroll
    for (int s = 0; s < DS; s++) P[s] = 1.f;
    float sdt = 0.f;

    __syncthreads();

    u16 dt_c = dt_p[0];
    u16 xs_c = xs_p[0];

    if (fast) {
        for (int l = 0; l < LC; l++) {
            u16 dt_n = dt_p[LDXZ];           // benign over-read at l=LC-1
            u16 xs_n = xs_p[DI];
            const float* bl = bcs + l * 32;
            floatx4 B0 = *(const floatx4*)(bl);
            floatx4 B1 = *(const floatx4*)(bl + 4);
            floatx4 B2 = *(const floatx4*)(bl + 8);
            floatx4 B3 = *(const floatx4*)(bl + 12);

            float dtv = b2f(dt_c);
            float xv  = b2f(xs_c);
            float bx = dtv * xv;
            sdt += dtv;
            float aa[DS];
            pow_tree(__expf(dtv * ad0), aa);
#pragma unroll
            for (int s = 0; s < DS; s++) {
                float Bv = (s < 4) ? B0[s] : (s < 8) ? B1[s - 4]
                         : (s < 12) ? B2[s - 8] : B3[s - 12];
                h[s] = aa[s] * h[s] + bx * Bv;
            }
            dt_c = dt_n; xs_c = xs_n;
            dt_p += LDXZ; xs_p += DI;
        }
        pow_tree(__expf(ad0 * sdt), P);
    } else {
        for (int l = 0; l < LC; l++) {
            u16 dt_n = dt_p[LDXZ];
            u16 xs_n = xs_p[DI];
            const float* bl = bcs + l * 32;
            floatx4 B0 = *(const floatx4*)(bl);
            floatx4 B1 = *(const floatx4*)(bl + 4);
            floatx4 B2 = *(const floatx4*)(bl + 8);
            floatx4 B3 = *(const floatx4*)(bl + 12);

            float dtv = b2f(dt_c);
            float xv  = b2f(xs_c);
            float bx = dtv * xv;
#pragma unroll
            for (int s = 0; s < DS; s++) {
                float Bv = (s < 4) ? B0[s] : (s < 8) ? B1[s - 4]
                         : (s < 12) ? B2[s - 8] : B3[s - 12];
                float a = __expf(dtv * adl[s]);
                h[s] = a * h[s] + bx * Bv;
                P[s] *= a;
            }
            dt_c = dt_n; xs_c = xs_n;
            dt_p += LDXZ; xs_p += DI;
        }
    }

    const size_t base = ((size_t)(b * NCHUNK + c) * DI + d) * DS;
#pragma unroll
    for (int s = 0; s < DS; s += 4) {
        floatx4 pv = {P[s], P[s+1], P[s+2], P[s+3]};
        floatx4 hv = {h[s], h[s+1], h[s+2], h[s+3]};
        *(floatx4*)(scr_P + base + s)    = pv;
        *(floatx4*)(scr_hend + base + s) = hv;
    }
}

__global__ __launch_bounds__(256) void scan_p2(
    float* __restrict__ scr_P, const float* __restrict__ scr_hend)
{
    const int t = blockIdx.x * 256 + threadIdx.x;   // (b, d, s)
    const int s = t & 15;
    const int d = (t >> 4) & (DI - 1);
    const int b = t >> 15;

    float hin = 0.f;
    for (int c = 0; c < NCHUNK; c++) {
        const size_t base = ((size_t)(b * NCHUNK + c) * DI + d) * DS + s;
        float p = scr_P[base];
        float he = scr_hend[base];
        scr_P[base] = hin;
        hin = p * hin + he;
    }
}

__global__ __launch_bounds__(256) void scan_p3(
    const u16* __restrict__ xz, const u16* xs, const float* __restrict__ bcf,
    const float* __restrict__ scr_hin, const float* __restrict__ A_log,
    const float* __restrict__ Dvec, u16* yg)
{
    __shared__ alignas(16) float bcs[LC * 32];   // 16 KB

    const int d = blockIdx.x * 256 + threadIdx.x;
    const int b = blockIdx.y;
    const int c = blockIdx.z;
    const int m0 = b * Ll + c * LC;

    {
        const float* bc_g = bcf + (size_t)m0 * 32;
#pragma unroll
        for (int j = 0; j < 4; j++) {
            int idx = j * 1024 + threadIdx.x * 4;
            *(floatx4*)(bcs + idx) = *(const floatx4*)(bc_g + idx);
        }
    }

    const float ad0 = -__expf(A_log[0]);
    float adl[DS];
    bool fast = true;
#pragma unroll
    for (int s = 0; s < DS; s++) {
        float av = -__expf(A_log[s]);
        adl[s] = av;
        float kr = (float)(s + 1);
        if (fabsf(av / ad0 - kr) > 1e-4f * kr) fast = false;
    }
    const float Dd = Dvec[d];

    const u16* dt_p = xz + (size_t)m0 * LDXZ + d;          // xr half = dt
    const u16* z_p  = xz + (size_t)m0 * LDXZ + 2048 + d;   // z half
    const u16* xs_p = xs + (size_t)m0 * DI + d;
    u16* yg_p = yg + (size_t)m0 * DI + d;

    float h[DS];
    const size_t base = ((size_t)(b * NCHUNK + c) * DI + d) * DS;
#pragma unroll
    for (int s = 0; s < DS; s += 4) {
        floatx4 hv = *(const floatx4*)(scr_hin + base + s);
        h[s] = hv[0]; h[s+1] = hv[1]; h[s+2] = hv[2]; h[s+3] = hv[3];
    }

    __syncthreads();

    u16 dt_c = dt_p[0];
    u16 xs_c = xs_p[0];
    u16 z_c  = z_p[0];

    for (int l = 0; l < LC; l++) {
        u16 dt_n = dt_p[LDXZ];
        u16 xs_n = xs_p[DI];
        u16 z_n  = z_p[LDXZ];
        const float* bl = bcs + l * 32;
        floatx4 Bq[4], Cq[4];
#pragma unroll
        for (int q = 0; q < 4; q++) {
            Bq[q] = *(const floatx4*)(bl + q * 4);
            Cq[q] = *(const floatx4*)(bl + 16 + q * 4);
        }

        float dtv = b2f(dt_c);
        float xv  = b2f(xs_c);
        float bx = dtv * xv;
        float aa[DS];
        if (fast) {
            pow_tree(__expf(dtv * ad0), aa);
        } else {
#pragma unroll
            for (int s = 0; s < DS; s++) aa[s] = __expf(dtv * adl[s]);
        }
        float y0 = 0.f, y1 = 0.f, y2 = 0.f, y3 = 0.f;
#pragma unroll
        for (int q = 0; q < 4; q++) {
#pragma unroll
            for (int j = 0; j < 4; j++) {
                int s = q * 4 + j;
                h[s] = aa[s] * h[s] + bx * Bq[q][j];
            }
        }
#pragma unroll
        for (int j = 0; j < 4; j++) {
            y0 += h[j] * Cq[0][j];
            y1 += h[4 + j] * Cq[1][j];
            y2 += h[8 + j] * Cq[2][j];
            y3 += h[12 + j] * Cq[3][j];
        }
        float yt = ((y0 + y1) + (y2 + y3)) + Dd * xv;
        float zv = b2f(z_c);
        float g = zv / (1.f + __expf(-zv));
        yg_p[0] = f2b(yt * g);

        dt_c = dt_n; xs_c = xs_n; z_c = z_n;
        dt_p += LDXZ; xs_p += DI; z_p += LDXZ; yg_p += DI;
    }
}

// =====================================================================
extern "C" void kernel_launch(void* const* d_in, const int* in_sizes, int n_in,
                              void* d_out, int out_size, void* d_ws, size_t ws_size,
                              hipStream_t stream)
{
    const float* x      = (const float*)d_in[0];   // (B,L,DM)
    const float* W_in   = (const float*)d_in[1];   // (2*DI, DM)
    const float* conv_w = (const float*)d_in[2];   // (DI, KC)
    const float* conv_b = (const float*)d_in[3];   // (DI,)
    const float* A_log  = (const float*)d_in[4];   // (DS,)
    const float* Dvec   = (const float*)d_in[5];   // (DI,)
    const float* W_x    = (const float*)d_in[6];   // (96, DI)
    const float* W_dt   = (const float*)d_in[7];   // (DI, DTR)
    const float* b_dt   = (const float*)d_in[8];   // (DI,)
    const float* W_out  = (const float*)d_in[9];   // (DM, DI)

    // ---- workspace arena (bf16 u16 elements), ~133 MB total ----
    u16* ws = (u16*)d_ws;
    u16* xz    = ws;                 ws += (size_t)M * LDXZ;     // 67.1 MB (xr|z; xr half reused for dt)
    u16* xs    = ws;                 ws += (size_t)M * DI;       // 33.55 MB (yg in-place)
    u16* xbf   = ws;                 ws += (size_t)M * DM;       // 16.78 MB (x bf16 -> split-K parts -> scan scratch)
    u16* wibf  = ws;                 ws += (size_t)2 * DI * DM;  // 8.39 MB (reused as bcf)
    u16* wxp   = ws;                 ws += (size_t)NPAD * DI;    // 0.52 MB
    u16* wdtb  = ws;                 ws += (size_t)DI * DTR;     // 0.26 MB
    u16* woutb = ws;                 ws += (size_t)DM * DI;      // 4.19 MB
    u16* xdbl  = ws;                 ws += (size_t)M * NPAD;     // 2.10 MB
    u16* yg    = xs;                 // in-place
    float* part     = (float*)xbf;   // split-K partials (xbf dead after GEMM1)
    float* scr_P    = (float*)xbf;   // scan scratch (after reduce consumed parts)
    float* scr_hend = scr_P + (size_t)Bb * NCHUNK * DI * DS;
    float* bcf      = (float*)wibf;  // 1.05 MB (wibf dead after GEMM1)

    // 0) operand conversions (x + merged weight prep)
    cvt_f2b<<<(M * DM) / 256, 256, 0, stream>>>(x, xbf, M * DM);
    {
        constexpr int NTOT = 2 * DI * DM + NPAD * DI + DI * DTR + DM * DI;
        prep_weights<<<NTOT / 256, 256, 0, stream>>>(
            W_in, W_x, W_dt, W_out, wibf, wxp, wdtb, woutb);
    }

    // 1) xz = x @ W_in^T   (8192 x 4096, K=1024) — merged xr|z, 256^2 pipelined
    gemm256<0><<<dim3(LDXZ / 256, M / 256), 512, 0, stream>>>(
        xbf, wibf, xz, DM, DM, DM, LDXZ);

    // 2) conv + silu -> xs   (reads xr half of xz)
    conv_silu<<<M, 256, 0, stream>>>(xz, conv_w, conv_b, xs);

    // 3) x_dbl = xs @ wxp^T, split-K x4 -> fp32 parts, then reduce
    gemm_bt<4><<<dim3(1, M / 128, 4), 256, 0, stream>>>(
        xs, wxp, part, nullptr, DI / 4, DI, DI, NPAD);
    redk_gemm3<<<(M * 32) / 256, 256, 0, stream>>>(part, xdbl, bcf);

    // 4) dt = softplus(x_dbl[:, :64] @ W_dt^T + b_dt) -> xr half of xz
    gemm_bt<2><<<dim3(DI / 128, M / 128), 256, 0, stream>>>(
        xdbl, wdtb, xz, b_dt, DTR, NPAD, DTR, LDXZ);

    // 5) chunked scan
    scan_p1<<<dim3(DI / 256, Bb, NCHUNK), 256, 0, stream>>>(
        xz, xs, bcf, A_log, scr_P, scr_hend);
    scan_p2<<<(Bb * DI * DS) / 256, 256, 0, stream>>>(scr_P, scr_hend);
    scan_p3<<<dim3(DI / 256, Bb, NCHUNK), 256, 0, stream>>>(
        xz, xs, bcf, scr_P, A_log, Dvec, yg);

    // 6) out = yg @ W_out^T   (8192 x 1024, K=2048), fp32 store, 256^2 pipelined
    gemm256<1><<<dim3(DM / 256, M / 256), 512, 0, stream>>>(
        yg, woutb, d_out, DI, DI, DI, DM);
}

// Round 2
// 479.761 us; speedup vs baseline: 1.0730x; 1.0598x over previous
//
#include <hip/hip_runtime.h>
#include <math.h>

typedef unsigned short u16;
typedef unsigned int u32;

// ---- problem constants ----
constexpr int Bb = 4, Ll = 2048, DM = 1024, DI = 2048, DS = 16, DTR = 64, KC = 4;
constexpr int M = Bb * Ll;            // 8192 rows
constexpr int NPAD = 128;             // padded x_dbl width (64 + 2*16 = 96 -> 128)
constexpr int NCHUNK = 16;            // scan chunks
constexpr int LC = Ll / NCHUNK;       // 128 steps per chunk
constexpr int LDXZ = 4096;            // xz row stride (xr|z interleaved)

// ---- bf16 helpers on raw u16 ----
__device__ __forceinline__ float b2f(u16 u) {
    return __uint_as_float(((u32)u) << 16);
}
__device__ __forceinline__ u16 f2b(float f) {
    u32 x = __float_as_uint(f);
    u32 r = (x + 0x7fffu + ((x >> 16) & 1u)) >> 16;   // round-to-nearest-even
    return (u16)r;
}

typedef __attribute__((ext_vector_type(8))) short short8;
typedef __attribute__((ext_vector_type(4))) short short4v;
typedef __attribute__((ext_vector_type(4))) float floatx4;

// async global->LDS, 16B per lane; LDS dest = wave-uniform base + lane*16
__device__ __forceinline__ void gload16(const u16* g, u16* l) {
    __builtin_amdgcn_global_load_lds(
        (const __attribute__((address_space(1))) void*)g,
        (__attribute__((address_space(3))) void*)l,
        16, 0, 0);
}

// a^(s+1) for s=0..15 from base a, tree form (15 muls, depth 4)
__device__ __forceinline__ void pow_tree(float a, float* aa) {
    float a2 = a * a, a4 = a2 * a2, a8 = a4 * a4;
    aa[0] = a;        aa[1] = a2;       aa[2] = a * a2;   aa[3] = a4;
    aa[4] = a * a4;   aa[5] = a2 * a4;  aa[6] = aa[2] * a4; aa[7] = a8;
    aa[8] = a * a8;   aa[9] = a2 * a8;  aa[10] = aa[2] * a8; aa[11] = a4 * a8;
    aa[12] = aa[4] * a8; aa[13] = aa[5] * a8; aa[14] = aa[6] * a8; aa[15] = a8 * a8;
}

// =====================================================================
// Big-tile GEMM: C(MxN) = A(MxK) * B(NxK)^T, bf16 in, fp32 MFMA acc.
// 256x256 tile, 8 waves (2M x 4N), BK=32, 4-deep circular LDS buffer
// (128 KiB total), 2 phases per K-tile with counted vmcnt (T3+T4) and
// setprio around the MFMA cluster (T5).  K-chunk rotation swizzle
// (conflict-free ds_read_b128, SQ_LDS_BANK_CONFLICT=0 verified R1).
// Requires K % 32 == 0 and K >= 96.
// OUTM: 0 = bf16 store, 1 = fp32 store.
// =====================================================================
template<int OUTM>
__global__ __launch_bounds__(512, 2) void gemm256(
    const u16* __restrict__ A, const u16* __restrict__ Bm,
    void* __restrict__ Cv,
    int K, int lda, int ldb, int ldc)
{
    __shared__ alignas(16) u16 ldsA[4][256 * 32];   // 64 KiB
    __shared__ alignas(16) u16 ldsB[4][256 * 32];   // 64 KiB

    const int lane = threadIdx.x & 63;
    const int wave = threadIdx.x >> 6;     // 0..7
    const int wr = wave >> 2;              // 0..1  (M half of the tile)
    const int wc = wave & 3;               // 0..3  (N quarter)
    const int m0 = blockIdx.y * 256;
    const int n0 = blockIdx.x * 256;

    // ---- staging addresses: wave stages rows [wave*32, wave*32+32) ----
    const int lrow = lane >> 2;                               // 0..15
    const int skc  = (((lane & 3) + (lane >> 3)) & 3) * 8;    // k-chunk rotation
    const u16* pA = A  + (size_t)(m0 + wave * 32 + lrow) * lda + skc;
    const u16* pB = Bm + (size_t)(n0 + wave * 32 + lrow) * ldb + skc;
    const int ldst = wave * 1024;          // LDS element offset of this wave's 32 rows

    // ---- fragment read addresses (rotation-inverse slot) ----
    const int r16 = lane & 15;
    const int quad = lane >> 4;
    const int slot = (quad + 4 - ((r16 >> 1) & 3)) & 3;
    const int aoff = (wr * 128 + r16) * 32 + slot * 8;
    const int boff = (wc * 64  + r16) * 32 + slot * 8;

    const int NT = K >> 5;                 // K-tiles of 32

    floatx4 acc[8][4] = {};

    // ---- prologue: stage tiles 0,1,2 (12 loads/thread) ----
#pragma unroll
    for (int t = 0; t < 3; ++t) {
        gload16(pA + t * 32,            &ldsA[t][ldst]);
        gload16(pA + t * 32 + 16 * lda, &ldsA[t][ldst + 512]);
        gload16(pB + t * 32,            &ldsB[t][ldst]);
        gload16(pB + t * 32 + 16 * ldb, &ldsB[t][ldst + 512]);
    }
    asm volatile("s_waitcnt vmcnt(8)" ::: "memory");   // tile 0 landed
    __builtin_amdgcn_sched_barrier(0);
    __builtin_amdgcn_s_barrier();

    for (int t = 0; t < NT; ++t) {
        const u16* la = &ldsA[t & 3][aoff];
        const u16* lb = &ldsB[t & 3][boff];
        short8 af[8], bf[4];

        // ================= phase A: M-frags 0-3 x all N =================
#pragma unroll
        for (int i = 0; i < 4; ++i) af[i] = *(const short8*)(la + i * 512);
#pragma unroll
        for (int j = 0; j < 4; ++j) bf[j] = *(const short8*)(lb + j * 512);
        if (t + 3 < NT) {                  // stage A-tile of t+3 (buf freed at t-1)
            const u16* s = pA + (t + 3) * 32;
            u16* d = &ldsA[(t + 3) & 3][ldst];
            gload16(s, d);
            gload16(s + 16 * lda, d + 512);
        }
        __builtin_amdgcn_sched_barrier(0);
        __builtin_amdgcn_s_barrier();
        asm volatile("s_waitcnt lgkmcnt(0)" ::: "memory");
        __builtin_amdgcn_sched_barrier(0);
        __builtin_amdgcn_s_setprio(1);
#pragma unroll
        for (int i = 0; i < 4; ++i)
#pragma unroll
            for (int j = 0; j < 4; ++j)
                acc[i][j] = __builtin_amdgcn_mfma_f32_16x16x32_bf16(
                    af[i], bf[j], acc[i][j], 0, 0, 0);
        __builtin_amdgcn_s_setprio(0);
        __builtin_amdgcn_sched_barrier(0);
        __builtin_amdgcn_s_barrier();

        // ================= phase B: M-frags 4-7 x all N =================
#pragma unroll
        for (int i = 4; i < 8; ++i) af[i] = *(const short8*)(la + i * 512);
        if (t + 3 < NT) {                  // stage B-tile of t+3
            const u16* s = pB + (t + 3) * 32;
            u16* d = &ldsB[(t + 3) & 3][ldst];
            gload16(s, d);
            gload16(s + 16 * ldb, d + 512);
        }
        __builtin_amdgcn_sched_barrier(0);
        __builtin_amdgcn_s_barrier();
        asm volatile("s_waitcnt lgkmcnt(0)" ::: "memory");
        __builtin_amdgcn_sched_barrier(0);
        __builtin_amdgcn_s_setprio(1);
#pragma unroll
        for (int i = 4; i < 8; ++i)
#pragma unroll
            for (int j = 0; j < 4; ++j)
                acc[i][j] = __builtin_amdgcn_mfma_f32_16x16x32_bf16(
                    af[i], bf[j], acc[i][j], 0, 0, 0);
        __builtin_amdgcn_s_setprio(0);
        // counted vmcnt, once per K-tile; never 0 in steady state
        if (t + 3 < NT)      asm volatile("s_waitcnt vmcnt(8)" ::: "memory");
        else if (t + 2 < NT) asm volatile("s_waitcnt vmcnt(4)" ::: "memory");
        else if (t + 1 < NT) asm volatile("s_waitcnt vmcnt(0)" ::: "memory");
        __builtin_amdgcn_sched_barrier(0);
        __builtin_amdgcn_s_barrier();
    }

    // D layout: col = lane&15, row = quad*4 + r   [verified m89/m91]
    const int mw = m0 + wr * 128;
    const int nw = n0 + wc * 64;
    const int rb = quad * 4;
#pragma unroll
    for (int i = 0; i < 8; ++i) {
#pragma unroll
        for (int j = 0; j < 4; ++j) {
            const int n = nw + j * 16 + r16;
#pragma unroll
            for (int r = 0; r < 4; ++r) {
                const int m = mw + i * 16 + rb + r;
                float v = acc[i][j][r];
                if (OUTM == 1)
                    ((float*)Cv)[(size_t)m * ldc + n] = v;
                else
                    ((u16*)Cv)[(size_t)m * ldc + n] = f2b(v);
            }
        }
    }
}

// =====================================================================
// 256x128-tile variant for narrow-N GEMMs (GEMM6: N=1024).  Grid
// (N/128)x(M/256) = 256 blocks -> exactly 1 full round at 1 block/CU
// (96 KiB LDS).  8 waves as 4M x 2N, per-wave 64x64 output, single
// phase per K-tile (16 MFMA, 8 ds_read_b128, 3 gloads), counted
// vmcnt(6) (3 gloads x 3 tiles in flight).
// =====================================================================
template<int OUTM>
__global__ __launch_bounds__(512, 2) void gemm256n128(
    const u16* __restrict__ A, const u16* __restrict__ Bm,
    void* __restrict__ Cv,
    int K, int lda, int ldb, int ldc)
{
    __shared__ alignas(16) u16 ldsA[4][256 * 32];   // 64 KiB
    __shared__ alignas(16) u16 ldsB[4][128 * 32];   // 32 KiB

    const int lane = threadIdx.x & 63;
    const int wave = threadIdx.x >> 6;     // 0..7
    const int wr = wave >> 1;              // 0..3  (M quarter)
    const int wc = wave & 1;               // 0..1  (N half)
    const int m0 = blockIdx.y * 256;
    const int n0 = blockIdx.x * 128;

    // A: wave stages 32 rows (2 gloads); B: wave stages 16 rows (1 gload).
    const int lrow = lane >> 2;                               // 0..15
    const int skc  = (((lane & 3) + (lane >> 3)) & 3) * 8;    // k-chunk rotation
    const u16* pA = A  + (size_t)(m0 + wave * 32 + lrow) * lda + skc;
    const u16* pB = Bm + (size_t)(n0 + wave * 16 + lrow) * ldb + skc;
    const int ldstA = wave * 1024;
    const int ldstB = wave * 512;

    const int r16 = lane & 15;
    const int quad = lane >> 4;
    const int slot = (quad + 4 - ((r16 >> 1) & 3)) & 3;
    const int aoff = (wr * 64 + r16) * 32 + slot * 8;
    const int boff = (wc * 64 + r16) * 32 + slot * 8;

    const int NT = K >> 5;                 // K-tiles of 32

    floatx4 acc[4][4] = {};

    // ---- prologue: stage tiles 0,1,2 (9 loads/thread) ----
#pragma unroll
    for (int t = 0; t < 3; ++t) {
        gload16(pA + t * 32,            &ldsA[t][ldstA]);
        gload16(pA + t * 32 + 16 * lda, &ldsA[t][ldstA + 512]);
        gload16(pB + t * 32,            &ldsB[t][ldstB]);
    }
    asm volatile("s_waitcnt vmcnt(6)" ::: "memory");   // tile 0 landed
    __builtin_amdgcn_sched_barrier(0);
    __builtin_amdgcn_s_barrier();

    for (int t = 0; t < NT; ++t) {
        const u16* la = &ldsA[t & 3][aoff];
        const u16* lb = &ldsB[t & 3][boff];
        short8 af[4], bf[4];
#pragma unroll
        for (int i = 0; i < 4; ++i) af[i] = *(const short8*)(la + i * 512);
#pragma unroll
        for (int j = 0; j < 4; ++j) bf[j] = *(const short8*)(lb + j * 512);
        if (t + 3 < NT) {                  // stage tile t+3 (buf freed at t-1)
            const u16* sa = pA + (t + 3) * 32;
            u16* da = &ldsA[(t + 3) & 3][ldstA];
            gload16(sa, da);
            gload16(sa + 16 * lda, da + 512);
            gload16(pB + (t + 3) * 32, &ldsB[(t + 3) & 3][ldstB]);
        }
        __builtin_amdgcn_sched_barrier(0);
        __builtin_amdgcn_s_barrier();
        asm volatile("s_waitcnt lgkmcnt(0)" ::: "memory");
        __builtin_amdgcn_sched_barrier(0);
        __builtin_amdgcn_s_setprio(1);
#pragma unroll
        for (int i = 0; i < 4; ++i)
#pragma unroll
            for (int j = 0; j < 4; ++j)
                acc[i][j] = __builtin_amdgcn_mfma_f32_16x16x32_bf16(
                    af[i], bf[j], acc[i][j], 0, 0, 0);
        __builtin_amdgcn_s_setprio(0);
        if (t + 3 < NT)      asm volatile("s_waitcnt vmcnt(6)" ::: "memory");
        else if (t + 2 < NT) asm volatile("s_waitcnt vmcnt(3)" ::: "memory");
        else if (t + 1 < NT) asm volatile("s_waitcnt vmcnt(0)" ::: "memory");
        __builtin_amdgcn_sched_barrier(0);
        __builtin_amdgcn_s_barrier();
    }

    // D layout: col = lane&15, row = quad*4 + r   [verified m89/m91]
    const int mw = m0 + wr * 64;
    const int nw = n0 + wc * 64;
    const int rb = quad * 4;
#pragma unroll
    for (int i = 0; i < 4; ++i) {
#pragma unroll
        for (int j = 0; j < 4; ++j) {
            const int n = nw + j * 16 + r16;
#pragma unroll
            for (int r = 0; r < 4; ++r) {
                const int m = mw + i * 16 + rb + r;
                float v = acc[i][j][r];
                if (OUTM == 1)
                    ((float*)Cv)[(size_t)m * ldc + n] = v;
                else
                    ((u16*)Cv)[(size_t)m * ldc + n] = f2b(v);
            }
        }
    }
}

// =====================================================================
// C(MxN) = A(MxK) * B(NxK)^T, bf16 in, fp32 MFMA acc.  m97 structure
// + k-chunk rotation swizzle (conflict-free ds_read_b128).
// OUTM: 2 = softplus(acc + bias[n]) bf16,
//       4 = split-K partial: fp32 store, k-slice = blockIdx.z
// (kept for the small-K / small-N GEMMs)
// =====================================================================
template<int OUTM>
__global__ __launch_bounds__(256) void gemm_bt(
    const u16* __restrict__ A, const u16* __restrict__ Bm,
    void* __restrict__ Cv, const float* __restrict__ bias,
    int K, int lda, int ldb, int ldc)
{
    __shared__ alignas(16) u16 ldsA[128 * 32];
    __shared__ alignas(16) u16 ldsB[128 * 32];

    const int lane = threadIdx.x & 63;
    const int wave = threadIdx.x >> 6;
    const int wr = wave >> 1, wc = wave & 1;
    const int m0 = blockIdx.y * 128;
    const int n0 = blockIdx.x * 128;
    const int koff = (OUTM == 4) ? blockIdx.z * K : 0;

    const int srow = wave * 32 + (lane >> 2);
    const int skc  = (((lane & 3) + (lane >> 3)) & 3) * 8;
    const u16* Ag = A + (size_t)(m0 + srow) * lda + skc + koff;
    const u16* Bg = Bm + (size_t)(n0 + srow) * ldb + skc + koff;
    u16* lA = &ldsA[wave * 1024];
    u16* lB = &ldsB[wave * 1024];

    const int r16 = lane & 15;
    const int quad = lane >> 4;
    const int slot = (quad + 4 - ((r16 >> 1) & 3)) & 3;
    const u16* arow = &ldsA[(wr * 64 + r16) * 32 + slot * 8];
    const u16* brow = &ldsB[(wc * 64 + r16) * 32 + slot * 8];

    floatx4 acc[4][4] = {};

    for (int k0 = 0; k0 < K; k0 += 32) {
        gload16(Ag + k0,                    lA);
        gload16(Ag + k0 + (size_t)16 * lda, lA + 512);
        gload16(Bg + k0,                    lB);
        gload16(Bg + k0 + (size_t)16 * ldb, lB + 512);
        __syncthreads();

        short8 af[4], bf[4];
#pragma unroll
        for (int i = 0; i < 4; i++) af[i] = *(const short8*)(arow + i * 16 * 32);
#pragma unroll
        for (int j = 0; j < 4; j++) bf[j] = *(const short8*)(brow + j * 16 * 32);
#pragma unroll
        for (int i = 0; i < 4; i++)
#pragma unroll
            for (int j = 0; j < 4; j++)
                acc[i][j] = __builtin_amdgcn_mfma_f32_16x16x32_bf16(
                    af[i], bf[j], acc[i][j], 0, 0, 0);
        __syncthreads();
    }

    // D layout: col = lane&15, row = quad*4 + r   [verified m89/m91]
    const int mw = m0 + wr * 64;
    const int nw = n0 + wc * 64;
    const int rb = quad * 4;
#pragma unroll
    for (int i = 0; i < 4; i++) {
#pragma unroll
        for (int j = 0; j < 4; j++) {
            const int n = nw + j * 16 + r16;
#pragma unroll
            for (int r = 0; r < 4; r++) {
                const int m = mw + i * 16 + rb + r;
                float v = acc[i][j][r];
                if (OUTM == 2) {
                    v += bias[n];
                    v = (v > 20.f) ? v : log1pf(__expf(v));
                }
                if (OUTM == 4)
                    ((float*)Cv)[((size_t)blockIdx.z * M + m) * ldc + n] = v;
                else if (OUTM == 1)
                    ((float*)Cv)[(size_t)m * ldc + n] = v;
                else
                    ((u16*)Cv)[(size_t)m * ldc + n] = f2b(v);
            }
        }
    }
}

// =====================================================================
// reduce 4 split-K fp32 partials -> bf16 xdbl + fp32 bcf sideband
// =====================================================================
__global__ __launch_bounds__(256) void redk_gemm3(
    const float* __restrict__ part, u16* __restrict__ xdbl,
    float* __restrict__ bcf)
{
    const int t = blockIdx.x * 256 + threadIdx.x;   // over M*32
    const int n4 = (t & 31) * 4;
    const int m = t >> 5;
    const size_t stride = (size_t)M * NPAD;
    const float* p = part + (size_t)m * NPAD + n4;
    floatx4 acc = *(const floatx4*)(p)
                + *(const floatx4*)(p + stride)
                + *(const floatx4*)(p + 2 * stride)
                + *(const floatx4*)(p + 3 * stride);
    short4v ob;
#pragma unroll
    for (int j = 0; j < 4; j++) ob[j] = (short)f2b(acc[j]);
    *(short4v*)(xdbl + (size_t)m * NPAD + n4) = ob;
    if (n4 >= 64 && n4 < 96)
        *(floatx4*)(bcf + (size_t)m * 32 + (n4 - 64)) = acc;
}

// =====================================================================
__global__ __launch_bounds__(256) void cvt_f2b(
    const float* __restrict__ in, u16* __restrict__ out, int n)
{
    int i = blockIdx.x * blockDim.x + threadIdx.x;
    if (i < n) out[i] = f2b(in[i]);
}

// merged weight prep: W_in cvt | W_x pad | W_dt cvt | W_out cvt
__global__ __launch_bounds__(256) void prep_weights(
    const float* __restrict__ W_in, const float* __restrict__ W_x,
    const float* __restrict__ W_dt, const float* __restrict__ W_out,
    u16* __restrict__ wibf, u16* __restrict__ wxp,
    u16* __restrict__ wdtb, u16* __restrict__ woutb)
{
    constexpr int N1 = 2 * DI * DM;          // 4194304
    constexpr int N2 = NPAD * DI;            // 262144
    constexpr int N3 = DI * DTR;             // 131072
    int idx = blockIdx.x * blockDim.x + threadIdx.x;
    if (idx < N1) {
        wibf[idx] = f2b(W_in[idx]);
    } else if (idx < N1 + N2) {
        int i = idx - N1;
        int r = i >> 11, c = i & 2047;
        wxp[i] = (r < 96) ? f2b(W_x[r * 2048 + c]) : (u16)0;
    } else if (idx < N1 + N2 + N3) {
        int i = idx - N1 - N2;
        wdtb[i] = f2b(W_dt[i]);
    } else {
        int i = idx - N1 - N2 - N3;
        woutb[i] = f2b(W_out[i]);
    }
}

// =====================================================================
// Depthwise causal conv (K=4) + SiLU, vectorized.
// =====================================================================
__global__ __launch_bounds__(256) void conv_silu(
    const u16* __restrict__ xz, const float* __restrict__ conv_w,
    const float* __restrict__ conv_b, u16* __restrict__ xs)
{
    const int m = blockIdx.x;
    const int d0 = threadIdx.x * 8;
    const int l = m & (Ll - 1);

    float acc[8];
    {
        floatx4 cb0 = *(const floatx4*)(conv_b + d0);
        floatx4 cb1 = *(const floatx4*)(conv_b + d0 + 4);
#pragma unroll
        for (int j = 0; j < 4; j++) { acc[j] = cb0[j]; acc[4 + j] = cb1[j]; }
    }
    float w[8][KC];
#pragma unroll
    for (int jd = 0; jd < 8; jd++) {
        floatx4 wv = *(const floatx4*)(conv_w + (d0 + jd) * KC);
#pragma unroll
        for (int k = 0; k < KC; k++) w[jd][k] = wv[k];
    }
#pragma unroll
    for (int k = 0; k < KC; k++) {
        int li = l - (KC - 1) + k;
        if (li >= 0) {
            short8 xv = *(const short8*)(xz + (size_t)(m - (KC - 1) + k) * LDXZ + d0);
#pragma unroll
            for (int jd = 0; jd < 8; jd++)
                acc[jd] += b2f((u16)xv[jd]) * w[jd][k];
        }
    }
    short8 o;
#pragma unroll
    for (int jd = 0; jd < 8; jd++) {
        float s = acc[jd] / (1.f + __expf(-acc[jd]));
        o[jd] = (short)f2b(s);
    }
    *(short8*)(xs + (size_t)m * DI + d0) = o;
}

// =====================================================================
// Chunked selective scan.  One THREAD per (channel, chunk); 16 states in
// registers; coalesced dt/xs/z with 2-deep scalar prefetch (loops are
// load-latency-bound at 2 waves/SIMD).  B/C panel staged into 16 KB LDS.
// Fast path (A_log = log(1..16), wave-uniform check): 1 exp + pow tree.
// =====================================================================
__global__ __launch_bounds__(256) void scan_p1(
    const u16* __restrict__ xzdt, const u16* __restrict__ xs,
    const float* __restrict__ bcf, const float* __restrict__ A_log,
    float* __restrict__ scr_P, float* __restrict__ scr_hend)
{
    __shared__ alignas(16) float bcs[LC * 32];   // 16 KB

    const int d = blockIdx.x * 256 + threadIdx.x;
    const int b = blockIdx.y;
    const int c = blockIdx.z;
    const int m0 = b * Ll + c * LC;

    // cooperative stage of the B/C panel (coalesced float4)
    {
        const float* bc_g = bcf + (size_t)m0 * 32;
#pragma unroll
        for (int j = 0; j < 4; j++) {
            int idx = j * 1024 + threadIdx.x * 4;
            *(floatx4*)(bcs + idx) = *(const floatx4*)(bc_g + idx);
        }
    }

    const float ad0 = -__expf(A_log[0]);
    float adl[DS];
    bool fast = true;
#pragma unroll
    for (int s = 0; s < DS; s++) {
        float av = -__expf(A_log[s]);
        adl[s] = av;
        float kr = (float)(s + 1);
        if (fabsf(av / ad0 - kr) > 1e-4f * kr) fast = false;
    }

    const u16* dt_p = xzdt + (size_t)m0 * LDXZ + d;
    const u16* xs_p = xs + (size_t)m0 * DI + d;

    float h[DS] = {};
    float P[DS];
#pragma unroll
    for (int s = 0; s < DS; s++) P[s] = 1.f;
    float sdt = 0.f;

    __syncthreads();

    // 2-deep prefetch (benign over-reads stay inside the workspace arena)
    u16 dt_c = dt_p[0],     xs_c = xs_p[0];
    u16 dt_1 = dt_p[LDXZ],  xs_1 = xs_p[DI];

    if (fast) {
        for (int l = 0; l < LC; l++) {
            u16 dt_2 = dt_p[2 * LDXZ];
            u16 xs_2 = xs_p[2 * DI];
            const float* bl = bcs + l * 32;
            floatx4 B0 = *(const floatx4*)(bl);
            floatx4 B1 = *(const floatx4*)(bl + 4);
            floatx4 B2 = *(const floatx4*)(bl + 8);
            floatx4 B3 = *(const floatx4*)(bl + 12);

            float dtv = b2f(dt_c);
            float xv  = b2f(xs_c);
            float bx = dtv * xv;
            sdt += dtv;
            float aa[DS];
            pow_tree(__expf(dtv * ad0), aa);
#pragma unroll
            for (int s = 0; s < DS; s++) {
                float Bv = (s < 4) ? B0[s] : (s < 8) ? B1[s - 4]
                         : (s < 12) ? B2[s - 8] : B3[s - 12];
                h[s] = aa[s] * h[s] + bx * Bv;
            }
            dt_c = dt_1; dt_1 = dt_2; xs_c = xs_1; xs_1 = xs_2;
            dt_p += LDXZ; xs_p += DI;
        }
        pow_tree(__expf(ad0 * sdt), P);
    } else {
        for (int l = 0; l < LC; l++) {
            u16 dt_2 = dt_p[2 * LDXZ];
            u16 xs_2 = xs_p[2 * DI];
            const float* bl = bcs + l * 32;
            floatx4 B0 = *(const floatx4*)(bl);
            floatx4 B1 = *(const floatx4*)(bl + 4);
            floatx4 B2 = *(const floatx4*)(bl + 8);
            floatx4 B3 = *(const floatx4*)(bl + 12);

            float dtv = b2f(dt_c);
            float xv  = b2f(xs_c);
            float bx = dtv * xv;
#pragma unroll
            for (int s = 0; s < DS; s++) {
                float Bv = (s < 4) ? B0[s] : (s < 8) ? B1[s - 4]
                         : (s < 12) ? B2[s - 8] : B3[s - 12];
                float a = __expf(dtv * adl[s]);
                h[s] = a * h[s] + bx * Bv;
                P[s] *= a;
            }
            dt_c = dt_1; dt_1 = dt_2; xs_c = xs_1; xs_1 = xs_2;
            dt_p += LDXZ; xs_p += DI;
        }
    }

    const size_t base = ((size_t)(b * NCHUNK + c) * DI + d) * DS;
#pragma unroll
    for (int s = 0; s < DS; s += 4) {
        floatx4 pv = {P[s], P[s+1], P[s+2], P[s+3]};
        floatx4 hv = {h[s], h[s+1], h[s+2], h[s+3]};
        *(floatx4*)(scr_P + base + s)    = pv;
        *(floatx4*)(scr_hend + base + s) = hv;
    }
}

__global__ __launch_bounds__(256) void scan_p2(
    float* __restrict__ scr_P, const float* __restrict__ scr_hend)
{
    const int t = blockIdx.x * 256 + threadIdx.x;   // (b, d, s)
    const int s = t & 15;
    const int d = (t >> 4) & (DI - 1);
    const int b = t >> 15;

    float hin = 0.f;
    for (int c = 0; c < NCHUNK; c++) {
        const size_t base = ((size_t)(b * NCHUNK + c) * DI + d) * DS + s;
        float p = scr_P[base];
        float he = scr_hend[base];
        scr_P[base] = hin;
        hin = p * hin + he;
    }
}

__global__ __launch_bounds__(256) void scan_p3(
    const u16* __restrict__ xz, const u16* xs, const float* __restrict__ bcf,
    const float* __restrict__ scr_hin, const float* __restrict__ A_log,
    const float* __restrict__ Dvec, u16* yg)
{
    __shared__ alignas(16) float bcs[LC * 32];   // 16 KB

    const int d = blockIdx.x * 256 + threadIdx.x;
    const int b = blockIdx.y;
    const int c = blockIdx.z;
    const int m0 = b * Ll + c * LC;

    {
        const float* bc_g = bcf + (size_t)m0 * 32;
#pragma unroll
        for (int j = 0; j < 4; j++) {
            int idx = j * 1024 + threadIdx.x * 4;
            *(floatx4*)(bcs + idx) = *(const floatx4*)(bc_g + idx);
        }
    }

    const float ad0 = -__expf(A_log[0]);
    float adl[DS];
    bool fast = true;
#pragma unroll
    for (int s = 0; s < DS; s++) {
        float av = -__expf(A_log[s]);
        adl[s] = av;
        float kr = (float)(s + 1);
        if (fabsf(av / ad0 - kr) > 1e-4f * kr) fast = false;
    }
    const float Dd = Dvec[d];

    const u16* dt_p = xz + (size_t)m0 * LDXZ + d;          // xr half = dt
    const u16* z_p  = xz + (size_t)m0 * LDXZ + 2048 + d;   // z half
    const u16* xs_p = xs + (size_t)m0 * DI + d;
    u16* yg_p = yg + (size_t)m0 * DI + d;

    float h[DS];
    const size_t base = ((size_t)(b * NCHUNK + c) * DI + d) * DS;
#pragma unroll
    for (int s = 0; s < DS; s += 4) {
        floatx4 hv = *(const floatx4*)(scr_hin + base + s);
        h[s] = hv[0]; h[s+1] = hv[1]; h[s+2] = hv[2]; h[s+3] = hv[3];
    }

    __syncthreads();

    // 2-deep prefetch
    u16 dt_c = dt_p[0],    dt_1 = dt_p[LDXZ];
    u16 xs_c = xs_p[0],    xs_1 = xs_p[DI];
    u16 z_c  = z_p[0],     z_1  = z_p[LDXZ];

    for (int l = 0; l < LC; l++) {
        u16 dt_2 = dt_p[2 * LDXZ];
        u16 xs_2 = xs_p[2 * DI];
        u16 z_2  = z_p[2 * LDXZ];
        const float* bl = bcs + l * 32;
        floatx4 Bq[4], Cq[4];
#pragma unroll
        for (int q = 0; q < 4; q++) {
            Bq[q] = *(const floatx4*)(bl + q * 4);
            Cq[q] = *(const floatx4*)(bl + 16 + q * 4);
        }

        float dtv = b2f(dt_c);
        float xv  = b2f(xs_c);
        float bx = dtv * xv;
        float aa[DS];
        if (fast) {
            pow_tree(__expf(dtv * ad0), aa);
        } else {
#pragma unroll
            for (int s = 0; s < DS; s++) aa[s] = __expf(dtv * adl[s]);
        }
        float y0 = 0.f, y1 = 0.f, y2 = 0.f, y3 = 0.f;
#pragma unroll
        for (int q = 0; q < 4; q++) {
#pragma unroll
            for (int j = 0; j < 4; j++) {
                int s = q * 4 + j;
                h[s] = aa[s] * h[s] + bx * Bq[q][j];
            }
        }
#pragma unroll
        for (int j = 0; j < 4; j++) {
            y0 += h[j] * Cq[0][j];
            y1 += h[4 + j] * Cq[1][j];
            y2 += h[8 + j] * Cq[2][j];
            y3 += h[12 + j] * Cq[3][j];
        }
        float yt = ((y0 + y1) + (y2 + y3)) + Dd * xv;
        float zv = b2f(z_c);
        float g = zv / (1.f + __expf(-zv));
        yg_p[0] = f2b(yt * g);

        dt_c = dt_1; dt_1 = dt_2;
        xs_c = xs_1; xs_1 = xs_2;
        z_c  = z_1;  z_1  = z_2;
        dt_p += LDXZ; xs_p += DI; z_p += LDXZ; yg_p += DI;
    }
}

// =====================================================================
extern "C" void kernel_launch(void* const* d_in, const int* in_sizes, int n_in,
                              void* d_out, int out_size, void* d_ws, size_t ws_size,
                              hipStream_t stream)
{
    const float* x      = (const float*)d_in[0];   // (B,L,DM)
    const float* W_in   = (const float*)d_in[1];   // (2*DI, DM)
    const float* conv_w = (const float*)d_in[2];   // (DI, KC)
    const float* conv_b = (const float*)d_in[3];   // (DI,)
    const float* A_log  = (const float*)d_in[4];   // (DS,)
    const float* Dvec   = (const float*)d_in[5];   // (DI,)
    const float* W_x    = (const float*)d_in[6];   // (96, DI)
    const float* W_dt   = (const float*)d_in[7];   // (DI, DTR)
    const float* b_dt   = (const float*)d_in[8];   // (DI,)
    const float* W_out  = (const float*)d_in[9];   // (DM, DI)

    // ---- workspace arena (bf16 u16 elements), ~133 MB total ----
    u16* ws = (u16*)d_ws;
    u16* xz    = ws;                 ws += (size_t)M * LDXZ;     // 67.1 MB (xr|z; xr half reused for dt)
    u16* xs    = ws;                 ws += (size_t)M * DI;       // 33.55 MB (yg in-place)
    u16* xbf   = ws;                 ws += (size_t)M * DM;       // 16.78 MB (x bf16 -> split-K parts -> scan scratch)
    u16* wibf  = ws;                 ws += (size_t)2 * DI * DM;  // 8.39 MB (reused as bcf)
    u16* wxp   = ws;                 ws += (size_t)NPAD * DI;    // 0.52 MB
    u16* wdtb  = ws;                 ws += (size_t)DI * DTR;     // 0.26 MB
    u16* woutb = ws;                 ws += (size_t)DM * DI;      // 4.19 MB
    u16* xdbl  = ws;                 ws += (size_t)M * NPAD;     // 2.10 MB
    u16* yg    = xs;                 // in-place
    float* part     = (float*)xbf;   // split-K partials (xbf dead after GEMM1)
    float* scr_P    = (float*)xbf;   // scan scratch (after reduce consumed parts)
    float* scr_hend = scr_P + (size_t)Bb * NCHUNK * DI * DS;
    float* bcf      = (float*)wibf;  // 1.05 MB (wibf dead after GEMM1)

    // 0) operand conversions (x + merged weight prep)
    cvt_f2b<<<(M * DM) / 256, 256, 0, stream>>>(x, xbf, M * DM);
    {
        constexpr int NTOT = 2 * DI * DM + NPAD * DI + DI * DTR + DM * DI;
        prep_weights<<<NTOT / 256, 256, 0, stream>>>(
            W_in, W_x, W_dt, W_out, wibf, wxp, wdtb, woutb);
    }

    // 1) xz = x @ W_in^T   (8192 x 4096, K=1024) — merged xr|z, 256^2 pipelined
    gemm256<0><<<dim3(LDXZ / 256, M / 256), 512, 0, stream>>>(
        xbf, wibf, xz, DM, DM, DM, LDXZ);

    // 2) conv + silu -> xs   (reads xr half of xz)
    conv_silu<<<M, 256, 0, stream>>>(xz, conv_w, conv_b, xs);

    // 3) x_dbl = xs @ wxp^T, split-K x4 -> fp32 parts, then reduce
    gemm_bt<4><<<dim3(1, M / 128, 4), 256, 0, stream>>>(
        xs, wxp, part, nullptr, DI / 4, DI, DI, NPAD);
    redk_gemm3<<<(M * 32) / 256, 256, 0, stream>>>(part, xdbl, bcf);

    // 4) dt = softplus(x_dbl[:, :64] @ W_dt^T + b_dt) -> xr half of xz
    gemm_bt<2><<<dim3(DI / 128, M / 128), 256, 0, stream>>>(
        xdbl, wdtb, xz, b_dt, DTR, NPAD, DTR, LDXZ);

    // 5) chunked scan
    scan_p1<<<dim3(DI / 256, Bb, NCHUNK), 256, 0, stream>>>(
        xz, xs, bcf, A_log, scr_P, scr_hend);
    scan_p2<<<(Bb * DI * DS) / 256, 256, 0, stream>>>(scr_P, scr_hend);
    scan_p3<<<dim3(DI / 256, Bb, NCHUNK), 256, 0, stream>>>(
        xz, xs, bcf, scr_P, A_log, Dvec, yg);

    // 6) out = yg @ W_out^T   (8192 x 1024, K=2048), 256x128-tile, 1 full round
    gemm256n128<1><<<dim3(DM / 128, M / 256), 512, 0, stream>>>(
        yg, woutb, d_out, DI, DI, DI, DM);
}

// Round 3
// 476.104 us; speedup vs baseline: 1.0813x; 1.0077x over previous
//
#include <hip/hip_runtime.h>
#include <math.h>

typedef unsigned short u16;
typedef unsigned int u32;

// ---- problem constants ----
constexpr int Bb = 4, Ll = 2048, DM = 1024, DI = 2048, DS = 16, DTR = 64, KC = 4;
constexpr int M = Bb * Ll;            // 8192 rows
constexpr int NPAD = 128;             // padded x_dbl width (64 + 2*16 = 96 -> 128)
constexpr int NCHUNK = 32;            // scan chunks (R3: 16 -> 32 for TLP)
constexpr int LC = Ll / NCHUNK;       // 64 steps per chunk
constexpr int LDXZ = 4096;            // xz row stride (xr|z interleaved)

// ---- bf16 helpers on raw u16 ----
__device__ __forceinline__ float b2f(u16 u) {
    return __uint_as_float(((u32)u) << 16);
}
__device__ __forceinline__ u16 f2b(float f) {
    u32 x = __float_as_uint(f);
    u32 r = (x + 0x7fffu + ((x >> 16) & 1u)) >> 16;   // round-to-nearest-even
    return (u16)r;
}

typedef __attribute__((ext_vector_type(8))) short short8;
typedef __attribute__((ext_vector_type(4))) short short4v;
typedef __attribute__((ext_vector_type(4))) float floatx4;

// async global->LDS, 16B per lane; LDS dest = wave-uniform base + lane*16
__device__ __forceinline__ void gload16(const u16* g, u16* l) {
    __builtin_amdgcn_global_load_lds(
        (const __attribute__((address_space(1))) void*)g,
        (__attribute__((address_space(3))) void*)l,
        16, 0, 0);
}

// a^(s+1) for s=0..15 from base a, tree form (15 muls, depth 4)
__device__ __forceinline__ void pow_tree(float a, float* aa) {
    float a2 = a * a, a4 = a2 * a2, a8 = a4 * a4;
    aa[0] = a;        aa[1] = a2;       aa[2] = a * a2;   aa[3] = a4;
    aa[4] = a * a4;   aa[5] = a2 * a4;  aa[6] = aa[2] * a4; aa[7] = a8;
    aa[8] = a * a8;   aa[9] = a2 * a8;  aa[10] = aa[2] * a8; aa[11] = a4 * a8;
    aa[12] = aa[4] * a8; aa[13] = aa[5] * a8; aa[14] = aa[6] * a8; aa[15] = a8 * a8;
}

// =====================================================================
// Big-tile GEMM: C(MxN) = A(MxK) * B(NxK)^T, bf16 in, fp32 MFMA acc.
// 256x256 tile, 8 waves (2M x 4N), BK=32, 4-deep circular LDS buffer
// (128 KiB total), 2 phases per K-tile with counted vmcnt (T3+T4) and
// setprio around the MFMA cluster (T5).  K-chunk rotation swizzle
// (conflict-free ds_read_b128, SQ_LDS_BANK_CONFLICT=0 verified R1).
// At K=1024 measures 814 TF ~= catalog's 848 TF level (m248). Kept as-is.
// OUTM: 0 = bf16 store, 1 = fp32 store.
// =====================================================================
template<int OUTM>
__global__ __launch_bounds__(512, 2) void gemm256(
    const u16* __restrict__ A, const u16* __restrict__ Bm,
    void* __restrict__ Cv,
    int K, int lda, int ldb, int ldc)
{
    __shared__ alignas(16) u16 ldsA[4][256 * 32];   // 64 KiB
    __shared__ alignas(16) u16 ldsB[4][256 * 32];   // 64 KiB

    const int lane = threadIdx.x & 63;
    const int wave = threadIdx.x >> 6;     // 0..7
    const int wr = wave >> 2;              // 0..1  (M half of the tile)
    const int wc = wave & 3;               // 0..3  (N quarter)
    const int m0 = blockIdx.y * 256;
    const int n0 = blockIdx.x * 256;

    const int lrow = lane >> 2;                               // 0..15
    const int skc  = (((lane & 3) + (lane >> 3)) & 3) * 8;    // k-chunk rotation
    const u16* pA = A  + (size_t)(m0 + wave * 32 + lrow) * lda + skc;
    const u16* pB = Bm + (size_t)(n0 + wave * 32 + lrow) * ldb + skc;
    const int ldst = wave * 1024;

    const int r16 = lane & 15;
    const int quad = lane >> 4;
    const int slot = (quad + 4 - ((r16 >> 1) & 3)) & 3;
    const int aoff = (wr * 128 + r16) * 32 + slot * 8;
    const int boff = (wc * 64  + r16) * 32 + slot * 8;

    const int NT = K >> 5;                 // K-tiles of 32

    floatx4 acc[8][4] = {};

    // ---- prologue: stage tiles 0,1,2 ----
#pragma unroll
    for (int t = 0; t < 3; ++t) {
        gload16(pA + t * 32,            &ldsA[t][ldst]);
        gload16(pA + t * 32 + 16 * lda, &ldsA[t][ldst + 512]);
        gload16(pB + t * 32,            &ldsB[t][ldst]);
        gload16(pB + t * 32 + 16 * ldb, &ldsB[t][ldst + 512]);
    }
    asm volatile("s_waitcnt vmcnt(8)" ::: "memory");   // tile 0 landed
    __builtin_amdgcn_sched_barrier(0);
    __builtin_amdgcn_s_barrier();

    for (int t = 0; t < NT; ++t) {
        const u16* la = &ldsA[t & 3][aoff];
        const u16* lb = &ldsB[t & 3][boff];
        short8 af[8], bf[4];

        // ================= phase A: M-frags 0-3 x all N =================
#pragma unroll
        for (int i = 0; i < 4; ++i) af[i] = *(const short8*)(la + i * 512);
#pragma unroll
        for (int j = 0; j < 4; ++j) bf[j] = *(const short8*)(lb + j * 512);
        if (t + 3 < NT) {                  // stage A-tile of t+3 (buf freed at t-1)
            const u16* s = pA + (t + 3) * 32;
            u16* d = &ldsA[(t + 3) & 3][ldst];
            gload16(s, d);
            gload16(s + 16 * lda, d + 512);
        }
        __builtin_amdgcn_sched_barrier(0);
        __builtin_amdgcn_s_barrier();
        asm volatile("s_waitcnt lgkmcnt(0)" ::: "memory");
        __builtin_amdgcn_sched_barrier(0);
        __builtin_amdgcn_s_setprio(1);
#pragma unroll
        for (int i = 0; i < 4; ++i)
#pragma unroll
            for (int j = 0; j < 4; ++j)
                acc[i][j] = __builtin_amdgcn_mfma_f32_16x16x32_bf16(
                    af[i], bf[j], acc[i][j], 0, 0, 0);
        __builtin_amdgcn_s_setprio(0);
        __builtin_amdgcn_sched_barrier(0);
        __builtin_amdgcn_s_barrier();

        // ================= phase B: M-frags 4-7 x all N =================
#pragma unroll
        for (int i = 4; i < 8; ++i) af[i] = *(const short8*)(la + i * 512);
        if (t + 3 < NT) {                  // stage B-tile of t+3
            const u16* s = pB + (t + 3) * 32;
            u16* d = &ldsB[(t + 3) & 3][ldst];
            gload16(s, d);
            gload16(s + 16 * ldb, d + 512);
        }
        __builtin_amdgcn_sched_barrier(0);
        __builtin_amdgcn_s_barrier();
        asm volatile("s_waitcnt lgkmcnt(0)" ::: "memory");
        __builtin_amdgcn_sched_barrier(0);
        __builtin_amdgcn_s_setprio(1);
#pragma unroll
        for (int i = 4; i < 8; ++i)
#pragma unroll
            for (int j = 0; j < 4; ++j)
                acc[i][j] = __builtin_amdgcn_mfma_f32_16x16x32_bf16(
                    af[i], bf[j], acc[i][j], 0, 0, 0);
        __builtin_amdgcn_s_setprio(0);
        // counted vmcnt, once per K-tile; never 0 in steady state
        if (t + 3 < NT)      asm volatile("s_waitcnt vmcnt(8)" ::: "memory");
        else if (t + 2 < NT) asm volatile("s_waitcnt vmcnt(4)" ::: "memory");
        else if (t + 1 < NT) asm volatile("s_waitcnt vmcnt(0)" ::: "memory");
        __builtin_amdgcn_sched_barrier(0);
        __builtin_amdgcn_s_barrier();
    }

    // D layout: col = lane&15, row = quad*4 + r   [verified m89/m91]
    const int mw = m0 + wr * 128;
    const int nw = n0 + wc * 64;
    const int rb = quad * 4;
#pragma unroll
    for (int i = 0; i < 8; ++i) {
#pragma unroll
        for (int j = 0; j < 4; ++j) {
            const int n = nw + j * 16 + r16;
#pragma unroll
            for (int r = 0; r < 4; ++r) {
                const int m = mw + i * 16 + rb + r;
                float v = acc[i][j][r];
                if (OUTM == 1)
                    ((float*)Cv)[(size_t)m * ldc + n] = v;
                else
                    ((u16*)Cv)[(size_t)m * ldc + n] = f2b(v);
            }
        }
    }
}

// =====================================================================
// 256x128-tile variant for narrow-N GEMMs (GEMM6: N=1024).
// R3: 3-deep circular LDS buffer (72 KiB) -> 2 blocks/CU (144 KiB/CU),
// inter-block TLP replaces the 4th pipeline stage.  8 waves as 4M x 2N,
// per-wave 64x64 output, single phase per K-tile (16 MFMA, 8 ds_read,
// 3 gloads), steady-state vmcnt(3).
// =====================================================================
template<int OUTM>
__global__ __launch_bounds__(512, 4) void gemm256n128(
    const u16* __restrict__ A, const u16* __restrict__ Bm,
    void* __restrict__ Cv,
    int K, int lda, int ldb, int ldc)
{
    __shared__ alignas(16) u16 ldsA[3][256 * 32];   // 48 KiB
    __shared__ alignas(16) u16 ldsB[3][128 * 32];   // 24 KiB

    const int lane = threadIdx.x & 63;
    const int wave = threadIdx.x >> 6;     // 0..7
    const int wr = wave >> 1;              // 0..3  (M quarter)
    const int wc = wave & 1;               // 0..1  (N half)
    const int m0 = blockIdx.y * 256;
    const int n0 = blockIdx.x * 128;

    // A: wave stages 32 rows (2 gloads); B: wave stages 16 rows (1 gload).
    const int lrow = lane >> 2;                               // 0..15
    const int skc  = (((lane & 3) + (lane >> 3)) & 3) * 8;    // k-chunk rotation
    const u16* pA = A  + (size_t)(m0 + wave * 32 + lrow) * lda + skc;
    const u16* pB = Bm + (size_t)(n0 + wave * 16 + lrow) * ldb + skc;
    const int ldstA = wave * 1024;
    const int ldstB = wave * 512;

    const int r16 = lane & 15;
    const int quad = lane >> 4;
    const int slot = (quad + 4 - ((r16 >> 1) & 3)) & 3;
    const int aoff = (wr * 64 + r16) * 32 + slot * 8;
    const int boff = (wc * 64 + r16) * 32 + slot * 8;

    const int NT = K >> 5;                 // K-tiles of 32

    floatx4 acc[4][4] = {};

    // ---- prologue: stage tiles 0,1 (6 loads/thread) ----
#pragma unroll
    for (int t = 0; t < 2; ++t) {
        gload16(pA + t * 32,            &ldsA[t][ldstA]);
        gload16(pA + t * 32 + 16 * lda, &ldsA[t][ldstA + 512]);
        gload16(pB + t * 32,            &ldsB[t][ldstB]);
    }
    asm volatile("s_waitcnt vmcnt(3)" ::: "memory");   // tile 0 landed
    __builtin_amdgcn_sched_barrier(0);
    __builtin_amdgcn_s_barrier();

    int bc = 0, bs = 2;                    // compute buf / stage buf (bc+2 mod 3)
    for (int t = 0; t < NT; ++t) {
        const u16* la = &ldsA[bc][aoff];
        const u16* lb = &ldsB[bc][boff];
        short8 af[4], bf[4];
#pragma unroll
        for (int i = 0; i < 4; ++i) af[i] = *(const short8*)(la + i * 512);
#pragma unroll
        for (int j = 0; j < 4; ++j) bf[j] = *(const short8*)(lb + j * 512);
        if (t + 2 < NT) {                  // stage tile t+2 (buf read at t-1)
            const u16* sa = pA + (t + 2) * 32;
            u16* da = &ldsA[bs][ldstA];
            gload16(sa, da);
            gload16(sa + 16 * lda, da + 512);
            gload16(pB + (t + 2) * 32, &ldsB[bs][ldstB]);
        }
        __builtin_amdgcn_sched_barrier(0);
        __builtin_amdgcn_s_barrier();
        asm volatile("s_waitcnt lgkmcnt(0)" ::: "memory");
        __builtin_amdgcn_sched_barrier(0);
        __builtin_amdgcn_s_setprio(1);
#pragma unroll
        for (int i = 0; i < 4; ++i)
#pragma unroll
            for (int j = 0; j < 4; ++j)
                acc[i][j] = __builtin_amdgcn_mfma_f32_16x16x32_bf16(
                    af[i], bf[j], acc[i][j], 0, 0, 0);
        __builtin_amdgcn_s_setprio(0);
        if (t + 2 < NT)      asm volatile("s_waitcnt vmcnt(3)" ::: "memory");
        else if (t + 1 < NT) asm volatile("s_waitcnt vmcnt(0)" ::: "memory");
        __builtin_amdgcn_sched_barrier(0);
        __builtin_amdgcn_s_barrier();
        bc = (bc == 2) ? 0 : bc + 1;
        bs = (bs == 2) ? 0 : bs + 1;
    }

    // D layout: col = lane&15, row = quad*4 + r   [verified m89/m91]
    const int mw = m0 + wr * 64;
    const int nw = n0 + wc * 64;
    const int rb = quad * 4;
#pragma unroll
    for (int i = 0; i < 4; ++i) {
#pragma unroll
        for (int j = 0; j < 4; ++j) {
            const int n = nw + j * 16 + r16;
#pragma unroll
            for (int r = 0; r < 4; ++r) {
                const int m = mw + i * 16 + rb + r;
                float v = acc[i][j][r];
                if (OUTM == 1)
                    ((float*)Cv)[(size_t)m * ldc + n] = v;
                else
                    ((u16*)Cv)[(size_t)m * ldc + n] = f2b(v);
            }
        }
    }
}

// =====================================================================
// C(MxN) = A(MxK) * B(NxK)^T, bf16 in, fp32 MFMA acc.  m97 structure
// + k-chunk rotation swizzle (conflict-free ds_read_b128).
// OUTM: 2 = softplus(acc + bias[n]) bf16,
//       4 = split-K partial: fp32 store, k-slice = blockIdx.z
// (kept for the small-K / small-N GEMMs)
// =====================================================================
template<int OUTM>
__global__ __launch_bounds__(256) void gemm_bt(
    const u16* __restrict__ A, const u16* __restrict__ Bm,
    void* __restrict__ Cv, const float* __restrict__ bias,
    int K, int lda, int ldb, int ldc)
{
    __shared__ alignas(16) u16 ldsA[128 * 32];
    __shared__ alignas(16) u16 ldsB[128 * 32];

    const int lane = threadIdx.x & 63;
    const int wave = threadIdx.x >> 6;
    const int wr = wave >> 1, wc = wave & 1;
    const int m0 = blockIdx.y * 128;
    const int n0 = blockIdx.x * 128;
    const int koff = (OUTM == 4) ? blockIdx.z * K : 0;

    const int srow = wave * 32 + (lane >> 2);
    const int skc  = (((lane & 3) + (lane >> 3)) & 3) * 8;
    const u16* Ag = A + (size_t)(m0 + srow) * lda + skc + koff;
    const u16* Bg = Bm + (size_t)(n0 + srow) * ldb + skc + koff;
    u16* lA = &ldsA[wave * 1024];
    u16* lB = &ldsB[wave * 1024];

    const int r16 = lane & 15;
    const int quad = lane >> 4;
    const int slot = (quad + 4 - ((r16 >> 1) & 3)) & 3;
    const u16* arow = &ldsA[(wr * 64 + r16) * 32 + slot * 8];
    const u16* brow = &ldsB[(wc * 64 + r16) * 32 + slot * 8];

    floatx4 acc[4][4] = {};

    for (int k0 = 0; k0 < K; k0 += 32) {
        gload16(Ag + k0,                    lA);
        gload16(Ag + k0 + (size_t)16 * lda, lA + 512);
        gload16(Bg + k0,                    lB);
        gload16(Bg + k0 + (size_t)16 * ldb, lB + 512);
        __syncthreads();

        short8 af[4], bf[4];
#pragma unroll
        for (int i = 0; i < 4; i++) af[i] = *(const short8*)(arow + i * 16 * 32);
#pragma unroll
        for (int j = 0; j < 4; j++) bf[j] = *(const short8*)(brow + j * 16 * 32);
#pragma unroll
        for (int i = 0; i < 4; i++)
#pragma unroll
            for (int j = 0; j < 4; j++)
                acc[i][j] = __builtin_amdgcn_mfma_f32_16x16x32_bf16(
                    af[i], bf[j], acc[i][j], 0, 0, 0);
        __syncthreads();
    }

    // D layout: col = lane&15, row = quad*4 + r   [verified m89/m91]
    const int mw = m0 + wr * 64;
    const int nw = n0 + wc * 64;
    const int rb = quad * 4;
#pragma unroll
    for (int i = 0; i < 4; i++) {
#pragma unroll
        for (int j = 0; j < 4; j++) {
            const int n = nw + j * 16 + r16;
#pragma unroll
            for (int r = 0; r < 4; r++) {
                const int m = mw + i * 16 + rb + r;
                float v = acc[i][j][r];
                if (OUTM == 2) {
                    v += bias[n];
                    v = (v > 20.f) ? v : log1pf(__expf(v));
                }
                if (OUTM == 4)
                    ((float*)Cv)[((size_t)blockIdx.z * M + m) * ldc + n] = v;
                else if (OUTM == 1)
                    ((float*)Cv)[(size_t)m * ldc + n] = v;
                else
                    ((u16*)Cv)[(size_t)m * ldc + n] = f2b(v);
            }
        }
    }
}

// =====================================================================
// reduce 4 split-K fp32 partials -> bf16 xdbl + fp32 bcf sideband
// =====================================================================
__global__ __launch_bounds__(256) void redk_gemm3(
    const float* __restrict__ part, u16* __restrict__ xdbl,
    float* __restrict__ bcf)
{
    const int t = blockIdx.x * 256 + threadIdx.x;   // over M*32
    const int n4 = (t & 31) * 4;
    const int m = t >> 5;
    const size_t stride = (size_t)M * NPAD;
    const float* p = part + (size_t)m * NPAD + n4;
    floatx4 acc = *(const floatx4*)(p)
                + *(const floatx4*)(p + stride)
                + *(const floatx4*)(p + 2 * stride)
                + *(const floatx4*)(p + 3 * stride);
    short4v ob;
#pragma unroll
    for (int j = 0; j < 4; j++) ob[j] = (short)f2b(acc[j]);
    *(short4v*)(xdbl + (size_t)m * NPAD + n4) = ob;
    if (n4 >= 64 && n4 < 96)
        *(floatx4*)(bcf + (size_t)m * 32 + (n4 - 64)) = acc;
}

// =====================================================================
// merged operand prep: x cvt | W_in cvt | W_x pad | W_dt cvt | W_out cvt
// =====================================================================
__global__ __launch_bounds__(256) void prep_all(
    const float* __restrict__ x, const float* __restrict__ W_in,
    const float* __restrict__ W_x, const float* __restrict__ W_dt,
    const float* __restrict__ W_out,
    u16* __restrict__ xbf, u16* __restrict__ wibf, u16* __restrict__ wxp,
    u16* __restrict__ wdtb, u16* __restrict__ woutb)
{
    constexpr int N0 = M * DM;               // 8388608
    constexpr int N1 = 2 * DI * DM;          // 4194304
    constexpr int N2 = NPAD * DI;            // 262144
    constexpr int N3 = DI * DTR;             // 131072
    int idx = blockIdx.x * blockDim.x + threadIdx.x;
    if (idx < N0) {
        xbf[idx] = f2b(x[idx]);
        return;
    }
    idx -= N0;
    if (idx < N1) {
        wibf[idx] = f2b(W_in[idx]);
    } else if (idx < N1 + N2) {
        int i = idx - N1;
        int r = i >> 11, c = i & 2047;
        wxp[i] = (r < 96) ? f2b(W_x[r * 2048 + c]) : (u16)0;
    } else if (idx < N1 + N2 + N3) {
        int i = idx - N1 - N2;
        wdtb[i] = f2b(W_dt[i]);
    } else {
        int i = idx - N1 - N2 - N3;
        woutb[i] = f2b(W_out[i]);
    }
}

// =====================================================================
// Depthwise causal conv (K=4) + SiLU, vectorized.
// =====================================================================
__global__ __launch_bounds__(256) void conv_silu(
    const u16* __restrict__ xz, const float* __restrict__ conv_w,
    const float* __restrict__ conv_b, u16* __restrict__ xs)
{
    const int m = blockIdx.x;
    const int d0 = threadIdx.x * 8;
    const int l = m & (Ll - 1);

    float acc[8];
    {
        floatx4 cb0 = *(const floatx4*)(conv_b + d0);
        floatx4 cb1 = *(const floatx4*)(conv_b + d0 + 4);
#pragma unroll
        for (int j = 0; j < 4; j++) { acc[j] = cb0[j]; acc[4 + j] = cb1[j]; }
    }
    float w[8][KC];
#pragma unroll
    for (int jd = 0; jd < 8; jd++) {
        floatx4 wv = *(const floatx4*)(conv_w + (d0 + jd) * KC);
#pragma unroll
        for (int k = 0; k < KC; k++) w[jd][k] = wv[k];
    }
#pragma unroll
    for (int k = 0; k < KC; k++) {
        int li = l - (KC - 1) + k;
        if (li >= 0) {
            short8 xv = *(const short8*)(xz + (size_t)(m - (KC - 1) + k) * LDXZ + d0);
#pragma unroll
            for (int jd = 0; jd < 8; jd++)
                acc[jd] += b2f((u16)xv[jd]) * w[jd][k];
        }
    }
    short8 o;
#pragma unroll
    for (int jd = 0; jd < 8; jd++) {
        float s = acc[jd] / (1.f + __expf(-acc[jd]));
        o[jd] = (short)f2b(s);
    }
    *(short8*)(xs + (size_t)m * DI + d0) = o;
}

// =====================================================================
// Chunked selective scan, NCHUNK=32 (1024 blocks -> 4 blocks/CU TLP).
// Inter-chunk state compressed via the exact identity
//   P_s = prod_l exp(dt_l * a_s) = exp(a_s * sum(dt))
// so p1 stores only h_end (16 floats) + sdt (1 float); p2 reconstructs
// P from sdt and runs IN-PLACE on the h array (batched alias-free loads).
// =====================================================================
__global__ __launch_bounds__(256) void scan_p1(
    const u16* __restrict__ xzdt, const u16* __restrict__ xs,
    const float* __restrict__ bcf, const float* __restrict__ A_log,
    float* __restrict__ scr_h, float* __restrict__ sdt_g)
{
    __shared__ alignas(16) float bcs[LC * 32];   // 8 KB

    const int d = blockIdx.x * 256 + threadIdx.x;
    const int b = blockIdx.y;
    const int c = blockIdx.z;
    const int m0 = b * Ll + c * LC;

    // cooperative stage of the B/C panel (coalesced float4)
    {
        const float* bc_g = bcf + (size_t)m0 * 32;
#pragma unroll
        for (int j = 0; j < 2; j++) {
            int idx = j * 1024 + threadIdx.x * 4;
            *(floatx4*)(bcs + idx) = *(const floatx4*)(bc_g + idx);
        }
    }

    const float ad0 = -__expf(A_log[0]);
    float adl[DS];
    bool fast = true;
#pragma unroll
    for (int s = 0; s < DS; s++) {
        float av = -__expf(A_log[s]);
        adl[s] = av;
        float kr = (float)(s + 1);
        if (fabsf(av / ad0 - kr) > 1e-4f * kr) fast = false;
    }

    const u16* dt_p = xzdt + (size_t)m0 * LDXZ + d;
    const u16* xs_p = xs + (size_t)m0 * DI + d;

    float h[DS] = {};
    float sdt = 0.f;

    __syncthreads();

    // 2-deep prefetch (benign over-reads stay inside the workspace arena)
    u16 dt_c = dt_p[0],     xs_c = xs_p[0];
    u16 dt_1 = dt_p[LDXZ],  xs_1 = xs_p[DI];

    if (fast) {
        for (int l = 0; l < LC; l++) {
            u16 dt_2 = dt_p[2 * LDXZ];
            u16 xs_2 = xs_p[2 * DI];
            const float* bl = bcs + l * 32;
            floatx4 B0 = *(const floatx4*)(bl);
            floatx4 B1 = *(const floatx4*)(bl + 4);
            floatx4 B2 = *(const floatx4*)(bl + 8);
            floatx4 B3 = *(const floatx4*)(bl + 12);

            float dtv = b2f(dt_c);
            float xv  = b2f(xs_c);
            float bx = dtv * xv;
            sdt += dtv;
            float aa[DS];
            pow_tree(__expf(dtv * ad0), aa);
#pragma unroll
            for (int s = 0; s < DS; s++) {
                float Bv = (s < 4) ? B0[s] : (s < 8) ? B1[s - 4]
                         : (s < 12) ? B2[s - 8] : B3[s - 12];
                h[s] = aa[s] * h[s] + bx * Bv;
            }
            dt_c = dt_1; dt_1 = dt_2; xs_c = xs_1; xs_1 = xs_2;
            dt_p += LDXZ; xs_p += DI;
        }
    } else {
        for (int l = 0; l < LC; l++) {
            u16 dt_2 = dt_p[2 * LDXZ];
            u16 xs_2 = xs_p[2 * DI];
            const float* bl = bcs + l * 32;
            floatx4 B0 = *(const floatx4*)(bl);
            floatx4 B1 = *(const floatx4*)(bl + 4);
            floatx4 B2 = *(const floatx4*)(bl + 8);
            floatx4 B3 = *(const floatx4*)(bl + 12);

            float dtv = b2f(dt_c);
            float xv  = b2f(xs_c);
            float bx = dtv * xv;
            sdt += dtv;
#pragma unroll
            for (int s = 0; s < DS; s++) {
                float Bv = (s < 4) ? B0[s] : (s < 8) ? B1[s - 4]
                         : (s < 12) ? B2[s - 8] : B3[s - 12];
                float a = __expf(dtv * adl[s]);
                h[s] = a * h[s] + bx * Bv;
            }
            dt_c = dt_1; dt_1 = dt_2; xs_c = xs_1; xs_1 = xs_2;
            dt_p += LDXZ; xs_p += DI;
        }
    }

    const size_t base = ((size_t)(b * NCHUNK + c) * DI + d) * DS;
#pragma unroll
    for (int s = 0; s < DS; s += 4) {
        floatx4 hv = {h[s], h[s+1], h[s+2], h[s+3]};
        *(floatx4*)(scr_h + base + s) = hv;
    }
    sdt_g[(size_t)(b * NCHUNK + c) * DI + d] = sdt;
}

// in-place chunk-prefix: scr_h holds h_end on entry, h_in on exit
__global__ __launch_bounds__(256) void scan_p2(
    float* __restrict__ scr_h, const float* __restrict__ sdt_g,
    const float* __restrict__ A_log)
{
    const int t = blockIdx.x * 256 + threadIdx.x;   // (b, d, s)
    const int s = t & 15;
    const int d = (t >> 4) & (DI - 1);
    const int b = t >> 15;
    const float adl = -__expf(A_log[s]);

    float he[NCHUNK], P[NCHUNK];
#pragma unroll
    for (int c = 0; c < NCHUNK; c++) {
        const size_t base = ((size_t)(b * NCHUNK + c) * DI + d) * DS + s;
        he[c] = scr_h[base];
        P[c] = adl * sdt_g[(size_t)(b * NCHUNK + c) * DI + d];
    }
#pragma unroll
    for (int c = 0; c < NCHUNK; c++) P[c] = __expf(P[c]);
    float hin = 0.f;
#pragma unroll
    for (int c = 0; c < NCHUNK; c++) {
        const size_t base = ((size_t)(b * NCHUNK + c) * DI + d) * DS + s;
        scr_h[base] = hin;
        hin = P[c] * hin + he[c];
    }
}

__global__ __launch_bounds__(256) void scan_p3(
    const u16* __restrict__ xz, const u16* xs, const float* __restrict__ bcf,
    const float* __restrict__ scr_hin, const float* __restrict__ A_log,
    const float* __restrict__ Dvec, u16* yg)
{
    __shared__ alignas(16) float bcs[LC * 32];   // 8 KB

    const int d = blockIdx.x * 256 + threadIdx.x;
    const int b = blockIdx.y;
    const int c = blockIdx.z;
    const int m0 = b * Ll + c * LC;

    {
        const float* bc_g = bcf + (size_t)m0 * 32;
#pragma unroll
        for (int j = 0; j < 2; j++) {
            int idx = j * 1024 + threadIdx.x * 4;
            *(floatx4*)(bcs + idx) = *(const floatx4*)(bc_g + idx);
        }
    }

    const float ad0 = -__expf(A_log[0]);
    float adl[DS];
    bool fast = true;
#pragma unroll
    for (int s = 0; s < DS; s++) {
        float av = -__expf(A_log[s]);
        adl[s] = av;
        float kr = (float)(s + 1);
        if (fabsf(av / ad0 - kr) > 1e-4f * kr) fast = false;
    }
    const float Dd = Dvec[d];

    const u16* dt_p = xz + (size_t)m0 * LDXZ + d;          // xr half = dt
    const u16* z_p  = xz + (size_t)m0 * LDXZ + 2048 + d;   // z half
    const u16* xs_p = xs + (size_t)m0 * DI + d;
    u16* yg_p = yg + (size_t)m0 * DI + d;

    float h[DS];
    const size_t base = ((size_t)(b * NCHUNK + c) * DI + d) * DS;
#pragma unroll
    for (int s = 0; s < DS; s += 4) {
        floatx4 hv = *(const floatx4*)(scr_hin + base + s);
        h[s] = hv[0]; h[s+1] = hv[1]; h[s+2] = hv[2]; h[s+3] = hv[3];
    }

    __syncthreads();

    // 2-deep prefetch
    u16 dt_c = dt_p[0],    dt_1 = dt_p[LDXZ];
    u16 xs_c = xs_p[0],    xs_1 = xs_p[DI];
    u16 z_c  = z_p[0],     z_1  = z_p[LDXZ];

    for (int l = 0; l < LC; l++) {
        u16 dt_2 = dt_p[2 * LDXZ];
        u16 xs_2 = xs_p[2 * DI];
        u16 z_2  = z_p[2 * LDXZ];
        const float* bl = bcs + l * 32;
        floatx4 Bq[4], Cq[4];
#pragma unroll
        for (int q = 0; q < 4; q++) {
            Bq[q] = *(const floatx4*)(bl + q * 4);
            Cq[q] = *(const floatx4*)(bl + 16 + q * 4);
        }

        float dtv = b2f(dt_c);
        float xv  = b2f(xs_c);
        float bx = dtv * xv;
        float aa[DS];
        if (fast) {
            pow_tree(__expf(dtv * ad0), aa);
        } else {
#pragma unroll
            for (int s = 0; s < DS; s++) aa[s] = __expf(dtv * adl[s]);
        }
        float y0 = 0.f, y1 = 0.f, y2 = 0.f, y3 = 0.f;
#pragma unroll
        for (int q = 0; q < 4; q++) {
#pragma unroll
            for (int j = 0; j < 4; j++) {
                int s = q * 4 + j;
                h[s] = aa[s] * h[s] + bx * Bq[q][j];
            }
        }
#pragma unroll
        for (int j = 0; j < 4; j++) {
            y0 += h[j] * Cq[0][j];
            y1 += h[4 + j] * Cq[1][j];
            y2 += h[8 + j] * Cq[2][j];
            y3 += h[12 + j] * Cq[3][j];
        }
        float yt = ((y0 + y1) + (y2 + y3)) + Dd * xv;
        float zv = b2f(z_c);
        float g = zv / (1.f + __expf(-zv));
        yg_p[0] = f2b(yt * g);

        dt_c = dt_1; dt_1 = dt_2;
        xs_c = xs_1; xs_1 = xs_2;
        z_c  = z_1;  z_1  = z_2;
        dt_p += LDXZ; xs_p += DI; z_p += LDXZ; yg_p += DI;
    }
}

// =====================================================================
extern "C" void kernel_launch(void* const* d_in, const int* in_sizes, int n_in,
                              void* d_out, int out_size, void* d_ws, size_t ws_size,
                              hipStream_t stream)
{
    const float* x      = (const float*)d_in[0];   // (B,L,DM)
    const float* W_in   = (const float*)d_in[1];   // (2*DI, DM)
    const float* conv_w = (const float*)d_in[2];   // (DI, KC)
    const float* conv_b = (const float*)d_in[3];   // (DI,)
    const float* A_log  = (const float*)d_in[4];   // (DS,)
    const float* Dvec   = (const float*)d_in[5];   // (DI,)
    const float* W_x    = (const float*)d_in[6];   // (96, DI)
    const float* W_dt   = (const float*)d_in[7];   // (DI, DTR)
    const float* b_dt   = (const float*)d_in[8];   // (DI,)
    const float* W_out  = (const float*)d_in[9];   // (DM, DI)

    // ---- workspace arena (bf16 u16 elements), ~133 MB total ----
    u16* ws = (u16*)d_ws;
    u16* xz    = ws;                 ws += (size_t)M * LDXZ;     // 67.1 MB (xr|z; xr half reused for dt)
    u16* xs    = ws;                 ws += (size_t)M * DI;       // 33.55 MB (yg in-place)
    u16* xbf   = ws;                 ws += (size_t)M * DM;       // 16.78 MB (x bf16 -> split-K parts -> scan h scratch)
    u16* wibf  = ws;                 ws += (size_t)2 * DI * DM;  // 8.39 MB (reused as bcf+sdt)
    u16* wxp   = ws;                 ws += (size_t)NPAD * DI;    // 0.52 MB
    u16* wdtb  = ws;                 ws += (size_t)DI * DTR;     // 0.26 MB
    u16* woutb = ws;                 ws += (size_t)DM * DI;      // 4.19 MB
    u16* xdbl  = ws;                 ws += (size_t)M * NPAD;     // 2.10 MB
    u16* yg    = xs;                 // in-place
    float* part  = (float*)xbf;      // split-K partials (xbf dead after GEMM1)
    float* scr_h = (float*)xbf;      // scan h scratch: B*NC*DI*DS*4B = 16.78 MB exactly
    float* bcf   = (float*)wibf;     // 1.05 MB (wibf dead after GEMM1)
    float* sdt_g = bcf + (size_t)M * 32;   // 1.05 MB, still inside wibf region

    // 0) merged operand prep (x cvt + all weight cvt/pad)
    {
        constexpr int NTOT = M * DM + 2 * DI * DM + NPAD * DI + DI * DTR + DM * DI;
        prep_all<<<NTOT / 256, 256, 0, stream>>>(
            x, W_in, W_x, W_dt, W_out, xbf, wibf, wxp, wdtb, woutb);
    }

    // 1) xz = x @ W_in^T   (8192 x 4096, K=1024) — merged xr|z, 256^2 pipelined
    gemm256<0><<<dim3(LDXZ / 256, M / 256), 512, 0, stream>>>(
        xbf, wibf, xz, DM, DM, DM, LDXZ);

    // 2) conv + silu -> xs   (reads xr half of xz)
    conv_silu<<<M, 256, 0, stream>>>(xz, conv_w, conv_b, xs);

    // 3) x_dbl = xs @ wxp^T, split-K x4 -> fp32 parts, then reduce
    gemm_bt<4><<<dim3(1, M / 128, 4), 256, 0, stream>>>(
        xs, wxp, part, nullptr, DI / 4, DI, DI, NPAD);
    redk_gemm3<<<(M * 32) / 256, 256, 0, stream>>>(part, xdbl, bcf);

    // 4) dt = softplus(x_dbl[:, :64] @ W_dt^T + b_dt) -> xr half of xz
    gemm_bt<2><<<dim3(DI / 128, M / 128), 256, 0, stream>>>(
        xdbl, wdtb, xz, b_dt, DTR, NPAD, DTR, LDXZ);

    // 5) chunked scan (NCHUNK=32)
    scan_p1<<<dim3(DI / 256, Bb, NCHUNK), 256, 0, stream>>>(
        xz, xs, bcf, A_log, scr_h, sdt_g);
    scan_p2<<<(Bb * DI * DS) / 256, 256, 0, stream>>>(scr_h, sdt_g, A_log);
    scan_p3<<<dim3(DI / 256, Bb, NCHUNK), 256, 0, stream>>>(
        xz, xs, bcf, scr_h, A_log, Dvec, yg);

    // 6) out = yg @ W_out^T   (8192 x 1024, K=2048), 256x128-tile, 3-deep, 2/CU
    gemm256n128<1><<<dim3(DM / 128, M / 256), 512, 0, stream>>>(
        yg, woutb, d_out, DI, DI, DI, DM);
}

// Round 4
// 463.146 us; speedup vs baseline: 1.1115x; 1.0280x over previous
//
#include <hip/hip_runtime.h>
#include <math.h>

typedef unsigned short u16;
typedef unsigned int u32;

// ---- problem constants ----
constexpr int Bb = 4, Ll = 2048, DM = 1024, DI = 2048, DS = 16, DTR = 64, KC = 4;
constexpr int M = Bb * Ll;            // 8192 rows
constexpr int NPAD = 128;             // padded x_dbl width (64 + 2*16 = 96 -> 128)
constexpr int NCHUNK = 32;            // scan chunks
constexpr int LC = Ll / NCHUNK;       // 64 steps per chunk
constexpr int LDXZ = 4096;            // xz row stride (xr|z interleaved)

// ---- bf16 helpers on raw u16 ----
__device__ __forceinline__ float b2f(u16 u) {
    return __uint_as_float(((u32)u) << 16);
}
__device__ __forceinline__ u16 f2b(float f) {
    u32 x = __float_as_uint(f);
    u32 r = (x + 0x7fffu + ((x >> 16) & 1u)) >> 16;   // round-to-nearest-even
    return (u16)r;
}

typedef __attribute__((ext_vector_type(8))) short short8;
typedef __attribute__((ext_vector_type(4))) short short4v;
typedef __attribute__((ext_vector_type(4))) float floatx4;

// async global->LDS, 16B per lane; LDS dest = wave-uniform base + lane*16
__device__ __forceinline__ void gload16(const u16* g, u16* l) {
    __builtin_amdgcn_global_load_lds(
        (const __attribute__((address_space(1))) void*)g,
        (__attribute__((address_space(3))) void*)l,
        16, 0, 0);
}

// a^(s+1) for s=0..15 from base a, tree form (15 muls, depth 4)
__device__ __forceinline__ void pow_tree(float a, float* aa) {
    float a2 = a * a, a4 = a2 * a2, a8 = a4 * a4;
    aa[0] = a;        aa[1] = a2;       aa[2] = a * a2;   aa[3] = a4;
    aa[4] = a * a4;   aa[5] = a2 * a4;  aa[6] = aa[2] * a4; aa[7] = a8;
    aa[8] = a * a8;   aa[9] = a2 * a8;  aa[10] = aa[2] * a8; aa[11] = a4 * a8;
    aa[12] = aa[4] * a8; aa[13] = aa[5] * a8; aa[14] = aa[6] * a8; aa[15] = a8 * a8;
}

// XCD-chunked bijective blockIdx swizzle (T1, m204-style).  Grid GX x GY,
// chunks of 8x x 4y assigned whole to one XCD so panel-sharing neighbor
// blocks hit the same L2.  Requires GX % 8 == 0 || GX == 8, GY % 4 == 0,
// and (GX*GY) % 256 == 0.
template<int GX, int GY>
__device__ __forceinline__ void xcd_swizzle(int& bx, int& by) {
    const int bid = blockIdx.y * GX + blockIdx.x;
    const int xcd = bid & 7;
    const int i = bid >> 3;                 // per-XCD index
    const int c_local = i >> 5;             // which chunk round on this XCD
    const int within = i & 31;              // 0..31 inside an 8x4 chunk
    const int lx = within & 7, ly = within >> 3;
    const int chunk = xcd + c_local * 8;    // global chunk id
    constexpr int CXN = GX / 8;             // x-chunks
    const int cx = chunk % CXN;
    const int cy = chunk / CXN;
    bx = cx * 8 + lx;
    by = cy * 4 + ly;
}

// =====================================================================
// Big-tile GEMM: C(MxN) = A(MxK) * B(NxK)^T, bf16 in, fp32 MFMA acc.
// 256x256 tile, 8 waves (2M x 4N), BK=32, 4-deep circular LDS buffer
// (128 KiB), ONE phase per K-tile (R4: 2 barriers + 1 lgkm drain per
// 32-MFMA cluster, was 4+2), counted vmcnt(8), setprio, XCD swizzle.
// K-chunk rotation swizzle (conflict-free ds_read_b128, verified R1).
// OUTM: 0 = bf16 store, 1 = fp32 store.  Grid must be (16, 32).
// =====================================================================
template<int OUTM>
__global__ __launch_bounds__(512, 2) void gemm256(
    const u16* __restrict__ A, const u16* __restrict__ Bm,
    void* __restrict__ Cv,
    int K, int lda, int ldb, int ldc)
{
    __shared__ alignas(16) u16 ldsA[4][256 * 32];   // 64 KiB
    __shared__ alignas(16) u16 ldsB[4][256 * 32];   // 64 KiB

    int bx, by;
    xcd_swizzle<16, 32>(bx, by);

    const int lane = threadIdx.x & 63;
    const int wave = threadIdx.x >> 6;     // 0..7
    const int wr = wave >> 2;              // 0..1  (M half of the tile)
    const int wc = wave & 3;               // 0..3  (N quarter)
    const int m0 = by * 256;
    const int n0 = bx * 256;

    const int lrow = lane >> 2;                               // 0..15
    const int skc  = (((lane & 3) + (lane >> 3)) & 3) * 8;    // k-chunk rotation
    const u16* pA = A  + (size_t)(m0 + wave * 32 + lrow) * lda + skc;
    const u16* pB = Bm + (size_t)(n0 + wave * 32 + lrow) * ldb + skc;
    const int ldst = wave * 1024;

    const int r16 = lane & 15;
    const int quad = lane >> 4;
    const int slot = (quad + 4 - ((r16 >> 1) & 3)) & 3;
    const int aoff = (wr * 128 + r16) * 32 + slot * 8;
    const int boff = (wc * 64  + r16) * 32 + slot * 8;

    const int NT = K >> 5;                 // K-tiles of 32

    floatx4 acc[8][4] = {};

    // ---- prologue: stage tiles 0,1,2 ----
#pragma unroll
    for (int t = 0; t < 3; ++t) {
        gload16(pA + t * 32,            &ldsA[t][ldst]);
        gload16(pA + t * 32 + 16 * lda, &ldsA[t][ldst + 512]);
        gload16(pB + t * 32,            &ldsB[t][ldst]);
        gload16(pB + t * 32 + 16 * ldb, &ldsB[t][ldst + 512]);
    }
    asm volatile("s_waitcnt vmcnt(8)" ::: "memory");   // tile 0 landed
    __builtin_amdgcn_sched_barrier(0);
    __builtin_amdgcn_s_barrier();

    for (int t = 0; t < NT; ++t) {
        const u16* la = &ldsA[t & 3][aoff];
        const u16* lb = &ldsB[t & 3][boff];
        short8 af[8], bf[4];
#pragma unroll
        for (int i = 0; i < 8; ++i) af[i] = *(const short8*)(la + i * 512);
#pragma unroll
        for (int j = 0; j < 4; ++j) bf[j] = *(const short8*)(lb + j * 512);
        if (t + 3 < NT) {                  // stage tile t+3 (buf freed at t-1)
            const u16* sA = pA + (t + 3) * 32;
            const u16* sB = pB + (t + 3) * 32;
            u16* dA = &ldsA[(t + 3) & 3][ldst];
            u16* dB = &ldsB[(t + 3) & 3][ldst];
            gload16(sA, dA);
            gload16(sA + 16 * lda, dA + 512);
            gload16(sB, dB);
            gload16(sB + 16 * ldb, dB + 512);
        }
        __builtin_amdgcn_sched_barrier(0);
        __builtin_amdgcn_s_barrier();      // pacing barrier
        asm volatile("s_waitcnt lgkmcnt(0)" ::: "memory");
        __builtin_amdgcn_sched_barrier(0);
        __builtin_amdgcn_s_setprio(1);
#pragma unroll
        for (int i = 0; i < 8; ++i)
#pragma unroll
            for (int j = 0; j < 4; ++j)
                acc[i][j] = __builtin_amdgcn_mfma_f32_16x16x32_bf16(
                    af[i], bf[j], acc[i][j], 0, 0, 0);
        __builtin_amdgcn_s_setprio(0);
        // counted vmcnt, once per K-tile; never 0 in steady state
        if (t + 3 < NT)      asm volatile("s_waitcnt vmcnt(8)" ::: "memory");
        else if (t + 2 < NT) asm volatile("s_waitcnt vmcnt(4)" ::: "memory");
        else if (t + 1 < NT) asm volatile("s_waitcnt vmcnt(0)" ::: "memory");
        __builtin_amdgcn_sched_barrier(0);
        __builtin_amdgcn_s_barrier();
    }

    // D layout: col = lane&15, row = quad*4 + r   [verified m89/m91]
    const int mw = m0 + wr * 128;
    const int nw = n0 + wc * 64;
    const int rb = quad * 4;
#pragma unroll
    for (int i = 0; i < 8; ++i) {
#pragma unroll
        for (int j = 0; j < 4; ++j) {
            const int n = nw + j * 16 + r16;
#pragma unroll
            for (int r = 0; r < 4; ++r) {
                const int m = mw + i * 16 + rb + r;
                float v = acc[i][j][r];
                if (OUTM == 1)
                    ((float*)Cv)[(size_t)m * ldc + n] = v;
                else
                    ((u16*)Cv)[(size_t)m * ldc + n] = f2b(v);
            }
        }
    }
}

// =====================================================================
// 256x128-tile variant for narrow-N GEMMs (GEMM6: N=1024).
// 3-deep circular LDS buffer (72 KiB) -> 2 blocks/CU, XCD swizzle (R4).
// 8 waves as 4M x 2N, per-wave 64x64 output, single phase per K-tile
// (16 MFMA, 8 ds_read, 3 gloads), steady-state vmcnt(3).
// Grid must be (8, 32).
// =====================================================================
template<int OUTM>
__global__ __launch_bounds__(512, 4) void gemm256n128(
    const u16* __restrict__ A, const u16* __restrict__ Bm,
    void* __restrict__ Cv,
    int K, int lda, int ldb, int ldc)
{
    __shared__ alignas(16) u16 ldsA[3][256 * 32];   // 48 KiB
    __shared__ alignas(16) u16 ldsB[3][128 * 32];   // 24 KiB

    int bx, by;
    xcd_swizzle<8, 32>(bx, by);

    const int lane = threadIdx.x & 63;
    const int wave = threadIdx.x >> 6;     // 0..7
    const int wr = wave >> 1;              // 0..3  (M quarter)
    const int wc = wave & 1;               // 0..1  (N half)
    const int m0 = by * 256;
    const int n0 = bx * 128;

    // A: wave stages 32 rows (2 gloads); B: wave stages 16 rows (1 gload).
    const int lrow = lane >> 2;                               // 0..15
    const int skc  = (((lane & 3) + (lane >> 3)) & 3) * 8;    // k-chunk rotation
    const u16* pA = A  + (size_t)(m0 + wave * 32 + lrow) * lda + skc;
    const u16* pB = Bm + (size_t)(n0 + wave * 16 + lrow) * ldb + skc;
    const int ldstA = wave * 1024;
    const int ldstB = wave * 512;

    const int r16 = lane & 15;
    const int quad = lane >> 4;
    const int slot = (quad + 4 - ((r16 >> 1) & 3)) & 3;
    const int aoff = (wr * 64 + r16) * 32 + slot * 8;
    const int boff = (wc * 64 + r16) * 32 + slot * 8;

    const int NT = K >> 5;                 // K-tiles of 32

    floatx4 acc[4][4] = {};

    // ---- prologue: stage tiles 0,1 (6 loads/thread) ----
#pragma unroll
    for (int t = 0; t < 2; ++t) {
        gload16(pA + t * 32,            &ldsA[t][ldstA]);
        gload16(pA + t * 32 + 16 * lda, &ldsA[t][ldstA + 512]);
        gload16(pB + t * 32,            &ldsB[t][ldstB]);
    }
    asm volatile("s_waitcnt vmcnt(3)" ::: "memory");   // tile 0 landed
    __builtin_amdgcn_sched_barrier(0);
    __builtin_amdgcn_s_barrier();

    int bc = 0, bs = 2;                    // compute buf / stage buf
    for (int t = 0; t < NT; ++t) {
        const u16* la = &ldsA[bc][aoff];
        const u16* lb = &ldsB[bc][boff];
        short8 af[4], bf[4];
#pragma unroll
        for (int i = 0; i < 4; ++i) af[i] = *(const short8*)(la + i * 512);
#pragma unroll
        for (int j = 0; j < 4; ++j) bf[j] = *(const short8*)(lb + j * 512);
        if (t + 2 < NT) {                  // stage tile t+2 (buf read at t-1)
            const u16* sa = pA + (t + 2) * 32;
            u16* da = &ldsA[bs][ldstA];
            gload16(sa, da);
            gload16(sa + 16 * lda, da + 512);
            gload16(pB + (t + 2) * 32, &ldsB[bs][ldstB]);
        }
        __builtin_amdgcn_sched_barrier(0);
        __builtin_amdgcn_s_barrier();
        asm volatile("s_waitcnt lgkmcnt(0)" ::: "memory");
        __builtin_amdgcn_sched_barrier(0);
        __builtin_amdgcn_s_setprio(1);
#pragma unroll
        for (int i = 0; i < 4; ++i)
#pragma unroll
            for (int j = 0; j < 4; ++j)
                acc[i][j] = __builtin_amdgcn_mfma_f32_16x16x32_bf16(
                    af[i], bf[j], acc[i][j], 0, 0, 0);
        __builtin_amdgcn_s_setprio(0);
        if (t + 2 < NT)      asm volatile("s_waitcnt vmcnt(3)" ::: "memory");
        else if (t + 1 < NT) asm volatile("s_waitcnt vmcnt(0)" ::: "memory");
        __builtin_amdgcn_sched_barrier(0);
        __builtin_amdgcn_s_barrier();
        bc = (bc == 2) ? 0 : bc + 1;
        bs = (bs == 2) ? 0 : bs + 1;
    }

    // D layout: col = lane&15, row = quad*4 + r   [verified m89/m91]
    const int mw = m0 + wr * 64;
    const int nw = n0 + wc * 64;
    const int rb = quad * 4;
#pragma unroll
    for (int i = 0; i < 4; ++i) {
#pragma unroll
        for (int j = 0; j < 4; ++j) {
            const int n = nw + j * 16 + r16;
#pragma unroll
            for (int r = 0; r < 4; ++r) {
                const int m = mw + i * 16 + rb + r;
                float v = acc[i][j][r];
                if (OUTM == 1)
                    ((float*)Cv)[(size_t)m * ldc + n] = v;
                else
                    ((u16*)Cv)[(size_t)m * ldc + n] = f2b(v);
            }
        }
    }
}

// =====================================================================
// C(MxN) = A(MxK) * B(NxK)^T, bf16 in, fp32 MFMA acc.  m97 structure
// + k-chunk rotation swizzle (conflict-free ds_read_b128).
// OUTM: 2 = softplus(acc + bias[n]) bf16,
//       4 = split-K partial: fp32 store, k-slice = blockIdx.z
// (kept for the small-K / small-N GEMMs)
// =====================================================================
template<int OUTM>
__global__ __launch_bounds__(256) void gemm_bt(
    const u16* __restrict__ A, const u16* __restrict__ Bm,
    void* __restrict__ Cv, const float* __restrict__ bias,
    int K, int lda, int ldb, int ldc)
{
    __shared__ alignas(16) u16 ldsA[128 * 32];
    __shared__ alignas(16) u16 ldsB[128 * 32];

    const int lane = threadIdx.x & 63;
    const int wave = threadIdx.x >> 6;
    const int wr = wave >> 1, wc = wave & 1;
    const int m0 = blockIdx.y * 128;
    const int n0 = blockIdx.x * 128;
    const int koff = (OUTM == 4) ? blockIdx.z * K : 0;

    const int srow = wave * 32 + (lane >> 2);
    const int skc  = (((lane & 3) + (lane >> 3)) & 3) * 8;
    const u16* Ag = A + (size_t)(m0 + srow) * lda + skc + koff;
    const u16* Bg = Bm + (size_t)(n0 + srow) * ldb + skc + koff;
    u16* lA = &ldsA[wave * 1024];
    u16* lB = &ldsB[wave * 1024];

    const int r16 = lane & 15;
    const int quad = lane >> 4;
    const int slot = (quad + 4 - ((r16 >> 1) & 3)) & 3;
    const u16* arow = &ldsA[(wr * 64 + r16) * 32 + slot * 8];
    const u16* brow = &ldsB[(wc * 64 + r16) * 32 + slot * 8];

    floatx4 acc[4][4] = {};

    for (int k0 = 0; k0 < K; k0 += 32) {
        gload16(Ag + k0,                    lA);
        gload16(Ag + k0 + (size_t)16 * lda, lA + 512);
        gload16(Bg + k0,                    lB);
        gload16(Bg + k0 + (size_t)16 * ldb, lB + 512);
        __syncthreads();

        short8 af[4], bf[4];
#pragma unroll
        for (int i = 0; i < 4; i++) af[i] = *(const short8*)(arow + i * 16 * 32);
#pragma unroll
        for (int j = 0; j < 4; j++) bf[j] = *(const short8*)(brow + j * 16 * 32);
#pragma unroll
        for (int i = 0; i < 4; i++)
#pragma unroll
            for (int j = 0; j < 4; j++)
                acc[i][j] = __builtin_amdgcn_mfma_f32_16x16x32_bf16(
                    af[i], bf[j], acc[i][j], 0, 0, 0);
        __syncthreads();
    }

    // D layout: col = lane&15, row = quad*4 + r   [verified m89/m91]
    const int mw = m0 + wr * 64;
    const int nw = n0 + wc * 64;
    const int rb = quad * 4;
#pragma unroll
    for (int i = 0; i < 4; i++) {
#pragma unroll
        for (int j = 0; j < 4; j++) {
            const int n = nw + j * 16 + r16;
#pragma unroll
            for (int r = 0; r < 4; r++) {
                const int m = mw + i * 16 + rb + r;
                float v = acc[i][j][r];
                if (OUTM == 2) {
                    v += bias[n];
                    v = (v > 20.f) ? v : log1pf(__expf(v));
                }
                if (OUTM == 4)
                    ((float*)Cv)[((size_t)blockIdx.z * M + m) * ldc + n] = v;
                else if (OUTM == 1)
                    ((float*)Cv)[(size_t)m * ldc + n] = v;
                else
                    ((u16*)Cv)[(size_t)m * ldc + n] = f2b(v);
            }
        }
    }
}

// =====================================================================
// reduce 4 split-K fp32 partials -> compact 64-wide bf16 xdbl (dt_r)
// + fp32 bcf sideband (cols 64..95).  Cols 96..127 are zero-pad, skipped.
// =====================================================================
__global__ __launch_bounds__(256) void redk_gemm3(
    const float* __restrict__ part, u16* __restrict__ xdbl,
    float* __restrict__ bcf)
{
    const int t = blockIdx.x * 256 + threadIdx.x;   // over M*24
    const int c4 = t % 24;
    const int m = t / 24;
    const int n4 = c4 * 4;                           // 0..92
    const size_t stride = (size_t)M * NPAD;
    const float* p = part + (size_t)m * NPAD + n4;
    floatx4 acc = *(const floatx4*)(p)
                + *(const floatx4*)(p + stride)
                + *(const floatx4*)(p + 2 * stride)
                + *(const floatx4*)(p + 3 * stride);
    if (n4 < 64) {
        short4v ob;
#pragma unroll
        for (int j = 0; j < 4; j++) ob[j] = (short)f2b(acc[j]);
        *(short4v*)(xdbl + (size_t)m * 64 + n4) = ob;
    } else {
        *(floatx4*)(bcf + (size_t)m * 32 + (n4 - 64)) = acc;
    }
}

// =====================================================================
// merged operand prep: x cvt | W_in cvt | W_x pad | W_dt cvt | W_out cvt
// =====================================================================
__global__ __launch_bounds__(256) void prep_all(
    const float* __restrict__ x, const float* __restrict__ W_in,
    const float* __restrict__ W_x, const float* __restrict__ W_dt,
    const float* __restrict__ W_out,
    u16* __restrict__ xbf, u16* __restrict__ wibf, u16* __restrict__ wxp,
    u16* __restrict__ wdtb, u16* __restrict__ woutb)
{
    constexpr int N0 = M * DM;               // 8388608
    constexpr int N1 = 2 * DI * DM;          // 4194304
    constexpr int N2 = NPAD * DI;            // 262144
    constexpr int N3 = DI * DTR;             // 131072
    int idx = blockIdx.x * blockDim.x + threadIdx.x;
    if (idx < N0) {
        xbf[idx] = f2b(x[idx]);
        return;
    }
    idx -= N0;
    if (idx < N1) {
        wibf[idx] = f2b(W_in[idx]);
    } else if (idx < N1 + N2) {
        int i = idx - N1;
        int r = i >> 11, c = i & 2047;
        wxp[i] = (r < 96) ? f2b(W_x[r * 2048 + c]) : (u16)0;
    } else if (idx < N1 + N2 + N3) {
        int i = idx - N1 - N2;
        wdtb[i] = f2b(W_dt[i]);
    } else {
        int i = idx - N1 - N2 - N3;
        woutb[i] = f2b(W_out[i]);
    }
}

// =====================================================================
// Depthwise causal conv (K=4) + SiLU, vectorized.
// =====================================================================
__global__ __launch_bounds__(256) void conv_silu(
    const u16* __restrict__ xz, const float* __restrict__ conv_w,
    const float* __restrict__ conv_b, u16* __restrict__ xs)
{
    const int m = blockIdx.x;
    const int d0 = threadIdx.x * 8;
    const int l = m & (Ll - 1);

    float acc[8];
    {
        floatx4 cb0 = *(const floatx4*)(conv_b + d0);
        floatx4 cb1 = *(const floatx4*)(conv_b + d0 + 4);
#pragma unroll
        for (int j = 0; j < 4; j++) { acc[j] = cb0[j]; acc[4 + j] = cb1[j]; }
    }
    float w[8][KC];
#pragma unroll
    for (int jd = 0; jd < 8; jd++) {
        floatx4 wv = *(const floatx4*)(conv_w + (d0 + jd) * KC);
#pragma unroll
        for (int k = 0; k < KC; k++) w[jd][k] = wv[k];
    }
#pragma unroll
    for (int k = 0; k < KC; k++) {
        int li = l - (KC - 1) + k;
        if (li >= 0) {
            short8 xv = *(const short8*)(xz + (size_t)(m - (KC - 1) + k) * LDXZ + d0);
#pragma unroll
            for (int jd = 0; jd < 8; jd++)
                acc[jd] += b2f((u16)xv[jd]) * w[jd][k];
        }
    }
    short8 o;
#pragma unroll
    for (int jd = 0; jd < 8; jd++) {
        float s = acc[jd] / (1.f + __expf(-acc[jd]));
        o[jd] = (short)f2b(s);
    }
    *(short8*)(xs + (size_t)m * DI + d0) = o;
}

// =====================================================================
// Chunked selective scan, NCHUNK=32 (1024 blocks).  Inter-chunk state
// compressed via P_s = exp(a_s * sum(dt)); p1 stores h_end + sdt; p2
// reconstructs P and runs in-place.
// =====================================================================
__global__ __launch_bounds__(256) void scan_p1(
    const u16* __restrict__ xzdt, const u16* __restrict__ xs,
    const float* __restrict__ bcf, const float* __restrict__ A_log,
    float* __restrict__ scr_h, float* __restrict__ sdt_g)
{
    __shared__ alignas(16) float bcs[LC * 32];   // 8 KB

    const int d = blockIdx.x * 256 + threadIdx.x;
    const int b = blockIdx.y;
    const int c = blockIdx.z;
    const int m0 = b * Ll + c * LC;

    {
        const float* bc_g = bcf + (size_t)m0 * 32;
#pragma unroll
        for (int j = 0; j < 2; j++) {
            int idx = j * 1024 + threadIdx.x * 4;
            *(floatx4*)(bcs + idx) = *(const floatx4*)(bc_g + idx);
        }
    }

    const float ad0 = -__expf(A_log[0]);
    float adl[DS];
    bool fast = true;
#pragma unroll
    for (int s = 0; s < DS; s++) {
        float av = -__expf(A_log[s]);
        adl[s] = av;
        float kr = (float)(s + 1);
        if (fabsf(av / ad0 - kr) > 1e-4f * kr) fast = false;
    }

    const u16* dt_p = xzdt + (size_t)m0 * LDXZ + d;
    const u16* xs_p = xs + (size_t)m0 * DI + d;

    float h[DS] = {};
    float sdt = 0.f;

    __syncthreads();

    u16 dt_c = dt_p[0],     xs_c = xs_p[0];
    u16 dt_1 = dt_p[LDXZ],  xs_1 = xs_p[DI];

    if (fast) {
        for (int l = 0; l < LC; l++) {
            u16 dt_2 = dt_p[2 * LDXZ];
            u16 xs_2 = xs_p[2 * DI];
            const float* bl = bcs + l * 32;
            floatx4 B0 = *(const floatx4*)(bl);
            floatx4 B1 = *(const floatx4*)(bl + 4);
            floatx4 B2 = *(const floatx4*)(bl + 8);
            floatx4 B3 = *(const floatx4*)(bl + 12);

            float dtv = b2f(dt_c);
            float xv  = b2f(xs_c);
            float bx = dtv * xv;
            sdt += dtv;
            float aa[DS];
            pow_tree(__expf(dtv * ad0), aa);
#pragma unroll
            for (int s = 0; s < DS; s++) {
                float Bv = (s < 4) ? B0[s] : (s < 8) ? B1[s - 4]
                         : (s < 12) ? B2[s - 8] : B3[s - 12];
                h[s] = aa[s] * h[s] + bx * Bv;
            }
            dt_c = dt_1; dt_1 = dt_2; xs_c = xs_1; xs_1 = xs_2;
            dt_p += LDXZ; xs_p += DI;
        }
    } else {
        for (int l = 0; l < LC; l++) {
            u16 dt_2 = dt_p[2 * LDXZ];
            u16 xs_2 = xs_p[2 * DI];
            const float* bl = bcs + l * 32;
            floatx4 B0 = *(const floatx4*)(bl);
            floatx4 B1 = *(const floatx4*)(bl + 4);
            floatx4 B2 = *(const floatx4*)(bl + 8);
            floatx4 B3 = *(const floatx4*)(bl + 12);

            float dtv = b2f(dt_c);
            float xv  = b2f(xs_c);
            float bx = dtv * xv;
            sdt += dtv;
#pragma unroll
            for (int s = 0; s < DS; s++) {
                float Bv = (s < 4) ? B0[s] : (s < 8) ? B1[s - 4]
                         : (s < 12) ? B2[s - 8] : B3[s - 12];
                float a = __expf(dtv * adl[s]);
                h[s] = a * h[s] + bx * Bv;
            }
            dt_c = dt_1; dt_1 = dt_2; xs_c = xs_1; xs_1 = xs_2;
            dt_p += LDXZ; xs_p += DI;
        }
    }

    const size_t base = ((size_t)(b * NCHUNK + c) * DI + d) * DS;
#pragma unroll
    for (int s = 0; s < DS; s += 4) {
        floatx4 hv = {h[s], h[s+1], h[s+2], h[s+3]};
        *(floatx4*)(scr_h + base + s) = hv;
    }
    sdt_g[(size_t)(b * NCHUNK + c) * DI + d] = sdt;
}

// in-place chunk-prefix: scr_h holds h_end on entry, h_in on exit
__global__ __launch_bounds__(256) void scan_p2(
    float* __restrict__ scr_h, const float* __restrict__ sdt_g,
    const float* __restrict__ A_log)
{
    const int t = blockIdx.x * 256 + threadIdx.x;   // (b, d, s)
    const int s = t & 15;
    const int d = (t >> 4) & (DI - 1);
    const int b = t >> 15;
    const float adl = -__expf(A_log[s]);

    float he[NCHUNK], P[NCHUNK];
#pragma unroll
    for (int c = 0; c < NCHUNK; c++) {
        const size_t base = ((size_t)(b * NCHUNK + c) * DI + d) * DS + s;
        he[c] = scr_h[base];
        P[c] = adl * sdt_g[(size_t)(b * NCHUNK + c) * DI + d];
    }
#pragma unroll
    for (int c = 0; c < NCHUNK; c++) P[c] = __expf(P[c]);
    float hin = 0.f;
#pragma unroll
    for (int c = 0; c < NCHUNK; c++) {
        const size_t base = ((size_t)(b * NCHUNK + c) * DI + d) * DS + s;
        scr_h[base] = hin;
        hin = P[c] * hin + he[c];
    }
}

__global__ __launch_bounds__(256) void scan_p3(
    const u16* __restrict__ xz, const u16* xs, const float* __restrict__ bcf,
    const float* __restrict__ scr_hin, const float* __restrict__ A_log,
    const float* __restrict__ Dvec, u16* yg)
{
    __shared__ alignas(16) float bcs[LC * 32];   // 8 KB

    const int d = blockIdx.x * 256 + threadIdx.x;
    const int b = blockIdx.y;
    const int c = blockIdx.z;
    const int m0 = b * Ll + c * LC;

    {
        const float* bc_g = bcf + (size_t)m0 * 32;
#pragma unroll
        for (int j = 0; j < 2; j++) {
            int idx = j * 1024 + threadIdx.x * 4;
            *(floatx4*)(bcs + idx) = *(const floatx4*)(bc_g + idx);
        }
    }

    const float ad0 = -__expf(A_log[0]);
    float adl[DS];
    bool fast = true;
#pragma unroll
    for (int s = 0; s < DS; s++) {
        float av = -__expf(A_log[s]);
        adl[s] = av;
        float kr = (float)(s + 1);
        if (fabsf(av / ad0 - kr) > 1e-4f * kr) fast = false;
    }
    const float Dd = Dvec[d];

    const u16* dt_p = xz + (size_t)m0 * LDXZ + d;          // xr half = dt
    const u16* z_p  = xz + (size_t)m0 * LDXZ + 2048 + d;   // z half
    const u16* xs_p = xs + (size_t)m0 * DI + d;
    u16* yg_p = yg + (size_t)m0 * DI + d;

    float h[DS];
    const size_t base = ((size_t)(b * NCHUNK + c) * DI + d) * DS;
#pragma unroll
    for (int s = 0; s < DS; s += 4) {
        floatx4 hv = *(const floatx4*)(scr_hin + base + s);
        h[s] = hv[0]; h[s+1] = hv[1]; h[s+2] = hv[2]; h[s+3] = hv[3];
    }

    __syncthreads();

    u16 dt_c = dt_p[0],    dt_1 = dt_p[LDXZ];
    u16 xs_c = xs_p[0],    xs_1 = xs_p[DI];
    u16 z_c  = z_p[0],     z_1  = z_p[LDXZ];

    for (int l = 0; l < LC; l++) {
        u16 dt_2 = dt_p[2 * LDXZ];
        u16 xs_2 = xs_p[2 * DI];
        u16 z_2  = z_p[2 * LDXZ];
        const float* bl = bcs + l * 32;
        floatx4 Bq[4], Cq[4];
#pragma unroll
        for (int q = 0; q < 4; q++) {
            Bq[q] = *(const floatx4*)(bl + q * 4);
            Cq[q] = *(const floatx4*)(bl + 16 + q * 4);
        }

        float dtv = b2f(dt_c);
        float xv  = b2f(xs_c);
        float bx = dtv * xv;
        float aa[DS];
        if (fast) {
            pow_tree(__expf(dtv * ad0), aa);
        } else {
#pragma unroll
            for (int s = 0; s < DS; s++) aa[s] = __expf(dtv * adl[s]);
        }
        float y0 = 0.f, y1 = 0.f, y2 = 0.f, y3 = 0.f;
#pragma unroll
        for (int q = 0; q < 4; q++) {
#pragma unroll
            for (int j = 0; j < 4; j++) {
                int s = q * 4 + j;
                h[s] = aa[s] * h[s] + bx * Bq[q][j];
            }
        }
#pragma unroll
        for (int j = 0; j < 4; j++) {
            y0 += h[j] * Cq[0][j];
            y1 += h[4 + j] * Cq[1][j];
            y2 += h[8 + j] * Cq[2][j];
            y3 += h[12 + j] * Cq[3][j];
        }
        float yt = ((y0 + y1) + (y2 + y3)) + Dd * xv;
        float zv = b2f(z_c);
        float g = zv / (1.f + __expf(-zv));
        yg_p[0] = f2b(yt * g);

        dt_c = dt_1; dt_1 = dt_2;
        xs_c = xs_1; xs_1 = xs_2;
        z_c  = z_1;  z_1  = z_2;
        dt_p += LDXZ; xs_p += DI; z_p += LDXZ; yg_p += DI;
    }
}

// =====================================================================
extern "C" void kernel_launch(void* const* d_in, const int* in_sizes, int n_in,
                              void* d_out, int out_size, void* d_ws, size_t ws_size,
                              hipStream_t stream)
{
    const float* x      = (const float*)d_in[0];   // (B,L,DM)
    const float* W_in   = (const float*)d_in[1];   // (2*DI, DM)
    const float* conv_w = (const float*)d_in[2];   // (DI, KC)
    const float* conv_b = (const float*)d_in[3];   // (DI,)
    const float* A_log  = (const float*)d_in[4];   // (DS,)
    const float* Dvec   = (const float*)d_in[5];   // (DI,)
    const float* W_x    = (const float*)d_in[6];   // (96, DI)
    const float* W_dt   = (const float*)d_in[7];   // (DI, DTR)
    const float* b_dt   = (const float*)d_in[8];   // (DI,)
    const float* W_out  = (const float*)d_in[9];   // (DM, DI)

    // ---- workspace arena (bf16 u16 elements), ~133 MB total ----
    u16* ws = (u16*)d_ws;
    u16* xz    = ws;                 ws += (size_t)M * LDXZ;     // 67.1 MB
    u16* xs    = ws;                 ws += (size_t)M * DI;       // 33.55 MB (yg in-place)
    u16* xbf   = ws;                 ws += (size_t)M * DM;       // 16.78 MB
    u16* wibf  = ws;                 ws += (size_t)2 * DI * DM;  // 8.39 MB (reused as bcf+sdt)
    u16* wxp   = ws;                 ws += (size_t)NPAD * DI;    // 0.52 MB
    u16* wdtb  = ws;                 ws += (size_t)DI * DTR;     // 0.26 MB
    u16* woutb = ws;                 ws += (size_t)DM * DI;      // 4.19 MB
    u16* xdbl  = ws;                 ws += (size_t)M * NPAD;     // 2.10 MB (only M*64 used)
    u16* yg    = xs;                 // in-place
    float* part  = (float*)xbf;      // split-K partials (xbf dead after GEMM1)
    float* scr_h = (float*)xbf;      // scan h scratch: B*NC*DI*DS*4B = 16.78 MB
    float* bcf   = (float*)wibf;     // 1.05 MB (wibf dead after GEMM1)
    float* sdt_g = bcf + (size_t)M * 32;   // 1.05 MB, inside wibf region

    // 0) merged operand prep
    {
        constexpr int NTOT = M * DM + 2 * DI * DM + NPAD * DI + DI * DTR + DM * DI;
        prep_all<<<NTOT / 256, 256, 0, stream>>>(
            x, W_in, W_x, W_dt, W_out, xbf, wibf, wxp, wdtb, woutb);
    }

    // 1) xz = x @ W_in^T   (8192 x 4096, K=1024), 256^2, 1-phase + swizzle
    gemm256<0><<<dim3(LDXZ / 256, M / 256), 512, 0, stream>>>(
        xbf, wibf, xz, DM, DM, DM, LDXZ);

    // 2) conv + silu -> xs
    conv_silu<<<M, 256, 0, stream>>>(xz, conv_w, conv_b, xs);

    // 3) x_dbl = xs @ wxp^T, split-K x4 -> fp32 parts, then reduce
    gemm_bt<4><<<dim3(1, M / 128, 4), 256, 0, stream>>>(
        xs, wxp, part, nullptr, DI / 4, DI, DI, NPAD);
    redk_gemm3<<<(M * 24) / 256, 256, 0, stream>>>(part, xdbl, bcf);

    // 4) dt = softplus(x_dbl[:, :64] @ W_dt^T + b_dt) -> xr half of xz
    gemm_bt<2><<<dim3(DI / 128, M / 128), 256, 0, stream>>>(
        xdbl, wdtb, xz, b_dt, DTR, 64, DTR, LDXZ);

    // 5) chunked scan (NCHUNK=32)
    scan_p1<<<dim3(DI / 256, Bb, NCHUNK), 256, 0, stream>>>(
        xz, xs, bcf, A_log, scr_h, sdt_g);
    scan_p2<<<(Bb * DI * DS) / 256, 256, 0, stream>>>(scr_h, sdt_g, A_log);
    scan_p3<<<dim3(DI / 256, Bb, NCHUNK), 256, 0, stream>>>(
        xz, xs, bcf, scr_h, A_log, Dvec, yg);

    // 6) out = yg @ W_out^T   (8192 x 1024, K=2048), 256x128, swizzled
    gemm256n128<1><<<dim3(DM / 128, M / 256), 512, 0, stream>>>(
        yg, woutb, d_out, DI, DI, DI, DM);
}